// Round 9
// baseline (320.134 us; speedup 1.0000x reference)
//
#include <hip/hip_runtime.h>
#include <hip/hip_fp16.h>

#define NFFT     4096
#define NC       2048      // complex FFT length (real-packed)
#define NHOP     1024
#define NK       2049
#define NBC      16
#define NSAMP    524288
#define NFRAMES  509
#define NT       256
#define STH      64        // k_smooth block size
#define SPSTR    1025      // spec row stride in uint2 (1024 pairs + bin1024)

#define A_COEFF 0.0022650046943f     // 1 - exp(-1/441)
#define R_COEFF 0.00022673165872f    // 1 - exp(-1/4410)
#define DB2LIN_LOG2 0.16609640474436812f  // log2(10)/20
#define DB_LOG2     6.02059991327962390f  // 20*log10(2)
#define PI_D 3.14159265358979323846264338327950288

// LDS swizzle: ~2-way max at every FFT stage
#define SW(e) ((e) + 7*((e)>>5))
#define SWSZ 2489      // SW(2047)+1  -> 19912 B LDS = 8 blocks/CU
#define TWN  292       // radix-8 stage tables: 256(A) + 32(B) + 4(C)
// ws header (bytes): tw12@0, tw3t@8192, wp@16384, pa@32768, pb@49152, mkq@65536
#define WSHDR 131072

__device__ __forceinline__ float2 cmul(float2 a, float2 b){
    return make_float2(a.x*b.x - a.y*b.y, a.x*b.y + a.y*b.x);
}
__device__ __forceinline__ float2 cmulc(float2 a, float2 b){   // a * conj(b)
    return make_float2(a.x*b.x + a.y*b.y, a.y*b.x - a.x*b.y);
}
__device__ __forceinline__ float2 f2add(float2 a, float2 b){ return make_float2(a.x+b.x, a.y+b.y); }
__device__ __forceinline__ float2 f2sub(float2 a, float2 b){ return make_float2(a.x-b.x, a.y-b.y); }

union HU { unsigned u; __half2 h; };
__device__ __forceinline__ unsigned packh2(float a, float b){
    HU x; x.h = __floats2half2_rn(a, b); return x.u;
}
__device__ __forceinline__ float2 unpackh2(unsigned v){
    HU x; x.u = v; float2 r = __half22float2(x.h); return r;
}

#define RSQRT2 0.70710678118654752f

// mixed-radix (8,8,8,4) digit scramble (host-side tables only)
__device__ __forceinline__ int revm(int p){
    return (p>>8) + 8*((p>>5)&7) + 64*((p>>2)&7) + 512*(p&3);
}
__device__ __forceinline__ int pmap(int k){
    return ((k&7)<<8) | (((k>>3)&7)<<5) | (((k>>6)&7)<<2) | ((k>>9)&3);
}
__device__ __forceinline__ int p_of_m(int m){ return ((m>>1)<<2) | (m&1); }

// ---------------- radix-8 forward core: butterfly then twiddle, in place ----------------
__device__ __forceinline__ void r8f(float2* d, const float4* __restrict__ tw12,
                                    const float2* __restrict__ tw3t, int n, int toff){
    float2 EA0=f2add(d[0],d[4]), EA1=f2sub(d[0],d[4]);
    float2 EB0=f2add(d[2],d[6]), EB1=f2sub(d[2],d[6]);
    float2 OA0=f2add(d[1],d[5]), OA1=f2sub(d[1],d[5]);
    float2 OB0=f2add(d[3],d[7]), OB1=f2sub(d[3],d[7]);
    float2 E0=f2add(EA0,EB0), E2=f2sub(EA0,EB0);
    float2 E1=make_float2(EA1.x+EB1.y, EA1.y-EB1.x);   // EA1 - i*EB1
    float2 E3=make_float2(EA1.x-EB1.y, EA1.y+EB1.x);   // EA1 + i*EB1
    float2 O0=f2add(OA0,OB0), O2=f2sub(OA0,OB0);
    float2 O1=make_float2(OA1.x+OB1.y, OA1.y-OB1.x);
    float2 O3=make_float2(OA1.x-OB1.y, OA1.y+OB1.x);
    const float c = RSQRT2;
    float2 t1=make_float2(c*(O1.x+O1.y), c*(O1.y-O1.x));   // w8^1 * O1
    float2 u2=make_float2(O2.y, -O2.x);                    // -i * O2
    float2 v3=make_float2(c*(O3.y-O3.x), -c*(O3.x+O3.y));  // w8^3 * O3
    float4 w12 = tw12[toff + n];
    float2 w1 = make_float2(w12.x, w12.y), w2 = make_float2(w12.z, w12.w);
    float2 w3 = tw3t[toff + n];
    float2 w4 = cmul(w2,w2), w5 = cmul(w2,w3), w6 = cmul(w3,w3), w7 = cmul(w3,w4);
    d[0] = f2add(E0,O0);
    d[1] = cmul(f2add(E1,t1), w1);
    d[2] = cmul(f2add(E2,u2), w2);
    d[3] = cmul(f2add(E3,v3), w3);
    d[4] = cmul(f2sub(E0,O0), w4);
    d[5] = cmul(f2sub(E1,t1), w5);
    d[6] = cmul(f2sub(E2,u2), w6);
    d[7] = cmul(f2sub(E3,v3), w7);
}

// ---------------- radix-8 inverse core: conj-twiddle then inverse butterfly ----------------
__device__ __forceinline__ void r8i(float2* d, const float4* __restrict__ tw12,
                                    const float2* __restrict__ tw3t, int n, int toff){
    float4 w12 = tw12[toff + n];
    float2 w1 = make_float2(w12.x, w12.y), w2 = make_float2(w12.z, w12.w);
    float2 w3 = tw3t[toff + n];
    float2 w4 = cmul(w2,w2), w5 = cmul(w2,w3), w6 = cmul(w3,w3), w7 = cmul(w3,w4);
    d[1]=cmulc(d[1],w1); d[2]=cmulc(d[2],w2); d[3]=cmulc(d[3],w3); d[4]=cmulc(d[4],w4);
    d[5]=cmulc(d[5],w5); d[6]=cmulc(d[6],w6); d[7]=cmulc(d[7],w7);
    float2 EA0=f2add(d[0],d[4]), EA1=f2sub(d[0],d[4]);
    float2 EB0=f2add(d[2],d[6]), EB1=f2sub(d[2],d[6]);
    float2 OA0=f2add(d[1],d[5]), OA1=f2sub(d[1],d[5]);
    float2 OB0=f2add(d[3],d[7]), OB1=f2sub(d[3],d[7]);
    float2 E0=f2add(EA0,EB0), E2=f2sub(EA0,EB0);
    float2 E1=make_float2(EA1.x-EB1.y, EA1.y+EB1.x);   // EA1 + i*EB1
    float2 E3=make_float2(EA1.x+EB1.y, EA1.y-EB1.x);
    float2 O0=f2add(OA0,OB0), O2=f2sub(OA0,OB0);
    float2 O1=make_float2(OA1.x-OB1.y, OA1.y+OB1.x);
    float2 O3=make_float2(OA1.x+OB1.y, OA1.y-OB1.x);
    const float c = RSQRT2;
    float2 t1=make_float2(c*(O1.x-O1.y), c*(O1.y+O1.x));    // conj(w8)*O1
    float2 u2=make_float2(-O2.y, O2.x);                     // +i*O2
    float2 v3=make_float2(-c*(O3.x+O3.y), c*(O3.x-O3.y));   // conj(w8^3)*O3
    d[0] = f2add(E0,O0);
    d[1] = f2add(E1,t1);
    d[2] = f2add(E2,u2);
    d[3] = f2add(E3,v3);
    d[4] = f2sub(E0,O0);
    d[5] = f2sub(E1,t1);
    d[6] = f2sub(E2,u2);
    d[7] = f2sub(E3,v3);
}

// rounds B, C, D of forward FFT (round A done by caller in registers)
__device__ __forceinline__ void fft_fwd_rest(float2* s, const float4* __restrict__ tw12,
                                             const float2* __restrict__ tw3t, int tid){
    __syncthreads();
    {   // round B, stride 32
        int base = (tid>>5)*256 + (tid&31);
        float2 d[8];
#pragma unroll
        for (int q = 0; q < 8; ++q) d[q] = s[SW(base + 32*q)];
        r8f(d, tw12, tw3t, tid&31, 256);
#pragma unroll
        for (int q = 0; q < 8; ++q) s[SW(base + 32*q)] = d[q];
    }
    __syncthreads();
    {   // round C, stride 4
        int base = (tid>>2)*32 + (tid&3);
        float2 d[8];
#pragma unroll
        for (int q = 0; q < 8; ++q) d[q] = s[SW(base + 4*q)];
        r8f(d, tw12, tw3t, tid&3, 288);
#pragma unroll
        for (int q = 0; q < 8; ++q) s[SW(base + 4*q)] = d[q];
    }
    __syncthreads();
    {   // round D: radix-4 span-1, trivial twiddle, contiguous 8/thread
        int g8 = 8*tid;
#pragma unroll
        for (int h = 0; h < 2; ++h) {
            int b4 = g8 + 4*h;
            float2 x0=s[SW(b4)], x1=s[SW(b4+1)], x2=s[SW(b4+2)], x3=s[SW(b4+3)];
            float2 A0=f2add(x0,x2), A1=f2sub(x0,x2);
            float2 B0=f2add(x1,x3), B1=f2sub(x1,x3);
            s[SW(b4)]   = f2add(A0,B0);
            s[SW(b4+1)] = make_float2(A1.x + B1.y, A1.y - B1.x);  // A1 - i*B1
            s[SW(b4+2)] = f2sub(A0,B0);
            s[SW(b4+3)] = make_float2(A1.x - B1.y, A1.y + B1.x);  // A1 + i*B1
        }
    }
    __syncthreads();
}

// rounds D', C', B' of inverse FFT; caller does round A' in registers afterwards
__device__ __forceinline__ void fft_inv_rest(float2* s, const float4* __restrict__ tw12,
                                             const float2* __restrict__ tw3t, int tid){
    {   // radix-4 span-1 inverse
        int g8 = 8*tid;
#pragma unroll
        for (int h = 0; h < 2; ++h) {
            int b4 = g8 + 4*h;
            float2 z0=s[SW(b4)], z1=s[SW(b4+1)], z2=s[SW(b4+2)], z3=s[SW(b4+3)];
            float2 A0=f2add(z0,z2), A1=f2sub(z0,z2);
            float2 B0=f2add(z1,z3), B1=f2sub(z1,z3);
            s[SW(b4)]   = f2add(A0,B0);
            s[SW(b4+1)] = make_float2(A1.x - B1.y, A1.y + B1.x);  // A1 + i*B1
            s[SW(b4+2)] = f2sub(A0,B0);
            s[SW(b4+3)] = make_float2(A1.x + B1.y, A1.y - B1.x);  // A1 - i*B1
        }
    }
    __syncthreads();
    {   // C' stride 4
        int base = (tid>>2)*32 + (tid&3);
        float2 d[8];
#pragma unroll
        for (int q = 0; q < 8; ++q) d[q] = s[SW(base + 4*q)];
        r8i(d, tw12, tw3t, tid&3, 288);
#pragma unroll
        for (int q = 0; q < 8; ++q) s[SW(base + 4*q)] = d[q];
    }
    __syncthreads();
    {   // B' stride 32
        int base = (tid>>5)*256 + (tid&31);
        float2 d[8];
#pragma unroll
        for (int q = 0; q < 8; ++q) d[q] = s[SW(base + 32*q)];
        r8i(d, tw12, tw3t, tid&31, 256);
#pragma unroll
        for (int q = 0; q < 8; ++q) s[SW(base + 32*q)] = d[q];
    }
    __syncthreads();
}

// q = {th, ks, 1/kw, slope}; input is |X|^2
__device__ __forceinline__ float gr_of2(float a2, float4 q){
    float mag_db = 0.5f * DB_LOG2 * log2f(fmaxf(a2, 1e-16f));
    float over = mag_db - q.x;
    float hard = (mag_db < q.x) ? 0.0f : over*q.w;
    float kf = fminf(fmaxf((mag_db - q.y)*q.z, 0.0f), 1.0f);
    float kneeg = kf*kf*over*q.w;
    float ke = 2.0f*q.x - q.y;
    return (mag_db >= q.y && mag_db <= ke) ? kneeg : hard;
}

__device__ __forceinline__ float2 scale_bin(float2 X, float g){
    float a2 = X.x*X.x + X.y*X.y;
    if (a2 >= 1e-16f) return make_float2(g*X.x, g*X.y);
    if (a2 > 0.f)  { float sc = g*1e-8f*rsqrtf(a2); return make_float2(sc*X.x, sc*X.y); }
    return make_float2(g*1e-8f, 0.f);
}

// bin index for thread-order gain slot q (k_init only)
__device__ __forceinline__ int bin_of_q(int q){
    if (q >= 2048) return 1024;
    int jj = q >> 8, t = q & 255;
    int m = t + 256*(jj>>1);
    int k = revm(p_of_m(m));
    if (jj & 1) return (k == 0) ? 2048 : 2048 - k;
    return k;
}

// ---------------- init: twiddles + pair table {W, p, p2} + params + makeup ----------------
__global__ __launch_bounds__(NT) void k_init(
    const float* __restrict__ thr, const float* __restrict__ ratio,
    const float* __restrict__ knee, const float* __restrict__ makeup,
    float4* __restrict__ tw12, float2* __restrict__ tw3t,
    float4* __restrict__ wp, float4* __restrict__ pa, float4* __restrict__ pb,
    float* __restrict__ mkq)
{
    int i = blockIdx.x*NT + threadIdx.x;
    if (i < TWN) {
        int n, len;
        if (i < 256)      { n = i;       len = 2048; }
        else if (i < 288) { n = i - 256; len = 256;  }
        else              { n = i - 288; len = 32;   }
        double ang = -2.0*PI_D*(double)n/(double)len;
        tw12[i] = make_float4((float)cos(ang), (float)sin(ang),
                              (float)cos(2.0*ang), (float)sin(2.0*ang));
        tw3t[i] = make_float2((float)cos(3.0*ang), (float)sin(3.0*ang));
    } else if (i < TWN + 1024) {
        int m = i - TWN;
        int p  = p_of_m(m);
        int k  = revm(p);
        int k2 = (k == 0) ? 2048 : 2048 - k;
        int p2 = pmap((2048 - k) & 2047);
        double ang = -PI_D*(double)k/2048.0;   // E(k/4096)
        wp[m] = make_float4((float)cos(ang), (float)sin(ang),
                            __int_as_float(p), __int_as_float(p2));
        float th = thr[k], ra = ratio[k], kw = knee[k];
        pa[m] = make_float4(th, th - 0.5f*kw, 1.0f/kw, 1.0f - 1.0f/ra);
        th = thr[k2]; ra = ratio[k2]; kw = knee[k2];
        pb[m] = make_float4(th, th - 0.5f*kw, 1.0f/kw, 1.0f - 1.0f/ra);
    } else if (i < TWN + 1024 + NK) {
        int q = i - TWN - 1024;
        mkq[q] = exp2f(makeup[bin_of_q(q)] * DB2LIN_LOG2);   // 10^(mk/20)
    }
}

// ---------------- kernel 1: STFT (round A fused with load); fp16 spec pairs + fp16 gr ----------------
template<int STORESPEC>
__global__ __launch_bounds__(NT, 8) void k_fwd(
    const float* __restrict__ audio, const float* __restrict__ window,
    const float* __restrict__ thr, const float* __restrict__ ratio,
    const float* __restrict__ knee,
    const float4* __restrict__ tw12, const float2* __restrict__ tw3t,
    const float4* __restrict__ wp, const float4* __restrict__ pa,
    const float4* __restrict__ pb,
    __half* __restrict__ gr, uint2* __restrict__ spec)
{
    __shared__ float2 s[SWSZ];
    const int tid = threadIdx.x;
    const int blk = blockIdx.x;
    const int bc  = blk / NFRAMES;
    const int f   = blk - bc*NFRAMES;

    const float2* a2c = (const float2*)(audio + (size_t)bc*NSAMP + (size_t)f*NHOP);
    const float2* w2c = (const float2*)window;
    {   // fused load + round A (stride 256), registers only
        float2 d[8];
#pragma unroll
        for (int q = 0; q < 8; ++q) {
            int n = tid + 256*q;
            float2 u = a2c[n], w = w2c[n];
            d[q] = make_float2(u.x*w.x, u.y*w.y);     // z[n] = x[2n]w + i x[2n+1]w
        }
        r8f(d, tw12, tw3t, tid, 0);
#pragma unroll
        for (int q = 0; q < 8; ++q) s[SW(tid + 256*q)] = d[q];
    }
    fft_fwd_rest(s, tw12, tw3t, tid);

    const size_t row = ((size_t)bc*NFRAMES + f) * NK;
    uint2* spx = spec + (size_t)(bc*NFRAMES + f) * SPSTR;
#pragma unroll
    for (int j = 0; j < 4; ++j) {
        int m  = tid + NT*j;
        float4 wpv = wp[m];
        int p  = __float_as_int(wpv.z);
        int p2 = __float_as_int(wpv.w);
        float2 Zk  = s[SW(p)];
        float2 Zk2 = s[SW(p2)];
        float2 Ze = make_float2(0.5f*(Zk.x + Zk2.x), 0.5f*(Zk.y - Zk2.y));
        float2 Zo = make_float2(0.5f*(Zk.y + Zk2.y), -0.5f*(Zk.x - Zk2.x));
        float2 W  = make_float2(wpv.x, wpv.y);
        float2 V  = cmul(W, Zo);
        float2 Xk  = f2add(Ze, V);                              // X[k]
        float2 Xk2 = make_float2(Ze.x - V.x, V.y - Ze.y);       // X[2048-k]
        if (STORESPEC)
            spx[m] = make_uint2(packh2(Xk.x, Xk.y), packh2(Xk2.x, Xk2.y));
        gr[row + tid + NT*(2*j)]     = __float2half_rn(gr_of2(Xk.x*Xk.x + Xk.y*Xk.y,   pa[m]));
        gr[row + tid + NT*(2*j + 1)] = __float2half_rn(gr_of2(Xk2.x*Xk2.x + Xk2.y*Xk2.y, pb[m]));
    }
    if (tid == 0) {   // self-paired bin 1024 at slot pmap(1024)=2: X = conj(Z)
        float2 Z = s[SW(2)];
        if (STORESPEC) spx[1024] = make_uint2(packh2(Z.x, -Z.y), 0u);
        float th = thr[1024], ra = ratio[1024], kw = knee[1024];
        float4 q = make_float4(th, th - 0.5f*kw, 1.0f/kw, 1.0f - 1.0f/ra);
        gr[row + 2048] = __float2half_rn(gr_of2(Z.x*Z.x + Z.y*Z.y, q));
    }
}

// ---------------- kernel 2: attack/release scan; fp16 gr(dB) -> fp16 linear gain ----------------
__global__ __launch_bounds__(STH) void k_smooth(
    __half* __restrict__ gr, const float* __restrict__ mkq)
{
    int gid = blockIdx.x*STH + threadIdx.x;
    if (gid >= NBC*NK) return;
    int bc = gid / NK;
    int q  = gid - bc*NK;
    float mkLin = mkq[q];
    __half* p = gr + (size_t)bc*NFRAMES*NK + q;

    float env = 0.f;
    float cur[8], nxt[8];
#pragma unroll
    for (int d = 0; d < 8; ++d) cur[d] = __half2float(p[(size_t)d*NK]);
    for (int c = 0; c < NFRAMES; c += 8) {
#pragma unroll
        for (int d = 0; d < 8; ++d) {              // prefetch next batch early
            int fn = c + 8 + d;
            if (fn < NFRAMES) nxt[d] = __half2float(p[(size_t)fn*NK]);
        }
#pragma unroll
        for (int d = 0; d < 8; ++d)
            if (c + d < NFRAMES) cur[d] = exp2f(cur[d] * -DB2LIN_LOG2);  // tgt
#pragma unroll
        for (int d = 0; d < 8; ++d)
            if (c + d < NFRAMES) {
                float tgt = cur[d];
                float coeff = (tgt < env) ? A_COEFF : R_COEFF;
                env = fmaf(coeff, tgt - env, env);
                cur[d] = fmaxf(env, 1e-8f) * mkLin;   // linear gain (log/exp cancels)
            }
#pragma unroll
        for (int d = 0; d < 8; ++d)
            if (c + d < NFRAMES) p[(size_t)(c+d)*NK] = __float2half_rn(cur[d]);
#pragma unroll
        for (int d = 0; d < 8; ++d) cur[d] = nxt[d];
    }
}

// repack scaled pair (XSk, XSk2) of bin k into packed-spectrum LDS slots (p, p2)
__device__ __forceinline__ void repack_pair(float2* s, float2 XSk, float2 XSk2,
                                            float2 W, int p, int p2){
    // Z'[k] = E + i*conj(W)*P ; Z'[k2] = conj(E) + i*W*conj(P)
    float2 E = make_float2(0.5f*(XSk.x + XSk2.x), 0.5f*(XSk.y - XSk2.y));
    float2 P = make_float2(0.5f*(XSk.x - XSk2.x), 0.5f*(XSk.y + XSk2.y));
    float2 Wc = make_float2(W.x, -W.y);
    float2 Q  = cmul(Wc, P);
    float2 Pc = make_float2(P.x, -P.y);
    float2 R  = cmul(W, Pc);
    s[SW(p)]  = make_float2(E.x - Q.y, E.y + Q.x);
    s[SW(p2)] = make_float2(E.x - R.y, R.x - E.y);
}

// MODE 0: spec -> scale -> ifft -> ca fp32 (separate buffer)
// MODE 1: spec -> scale -> ifft -> ca fp16 (in place over spec row)
// MODE 2: fallback — recompute fwd FFT from audio, scale, ifft, RMW out (4 passes)
template<int MODE>
__global__ __launch_bounds__(NT, 8) void k_inv(
    const float* __restrict__ audio, const float* __restrict__ window,
    const __half* __restrict__ gains,
    const float4* __restrict__ tw12, const float2* __restrict__ tw3t,
    const float4* __restrict__ wp,
    uint2* __restrict__ spec, float* __restrict__ caF,
    float* __restrict__ out, int pass, int nfp)
{
    __shared__ float2 s[SWSZ];
    const int tid = threadIdx.x;
    const int blk = blockIdx.x;
    int bc, f;
    if (MODE != 2) { bc = blk / NFRAMES; f = blk - bc*NFRAMES; }
    else           { bc = blk / nfp;     f = pass + 4*(blk - bc*nfp); }

    const float2* w2c = (const float2*)window;
    const __half* g = gains + ((size_t)bc*NFRAMES + f) * NK;
    uint2* spx = spec + (size_t)(bc*NFRAMES + f) * SPSTR;

    if (MODE != 2) {
        // scale + repack directly from fp16 spec pairs (no FFT, no unpack)
#pragma unroll
        for (int j = 0; j < 4; ++j) {
            int m = tid + NT*j;
            uint2 v = spx[m];
            float4 wpv = wp[m];
            float2 XSk  = scale_bin(unpackh2(v.x), __half2float(g[tid + NT*(2*j)]));
            float2 XSk2 = scale_bin(unpackh2(v.y), __half2float(g[tid + NT*(2*j + 1)]));
            repack_pair(s, XSk, XSk2, make_float2(wpv.x, wpv.y),
                        __float_as_int(wpv.z), __float_as_int(wpv.w));
        }
        if (tid == 0) {
            uint2 v = spx[1024];
            float2 XS = scale_bin(unpackh2(v.x), __half2float(g[2048]));
            s[SW(2)] = make_float2(XS.x, -XS.y);     // Z' = conj(XS)
        }
        __syncthreads();
    } else {
        {   // fused load + forward round A
            const float2* a2c = (const float2*)(audio + (size_t)bc*NSAMP + (size_t)f*NHOP);
            float2 d[8];
#pragma unroll
            for (int q = 0; q < 8; ++q) {
                int n = tid + 256*q;
                float2 u = a2c[n], w = w2c[n];
                d[q] = make_float2(u.x*w.x, u.y*w.y);
            }
            r8f(d, tw12, tw3t, tid, 0);
#pragma unroll
            for (int q = 0; q < 8; ++q) s[SW(tid + 256*q)] = d[q];
        }
        fft_fwd_rest(s, tw12, tw3t, tid);
        // unpack + scale + repack in place
#pragma unroll
        for (int j = 0; j < 4; ++j) {
            int m = tid + NT*j;
            float4 wpv = wp[m];
            int p  = __float_as_int(wpv.z);
            int p2 = __float_as_int(wpv.w);
            float2 Zk  = s[SW(p)];
            float2 Zk2 = s[SW(p2)];
            float2 Ze = make_float2(0.5f*(Zk.x + Zk2.x), 0.5f*(Zk.y - Zk2.y));
            float2 Zo = make_float2(0.5f*(Zk.y + Zk2.y), -0.5f*(Zk.x - Zk2.x));
            float2 W  = make_float2(wpv.x, wpv.y);
            float2 V  = cmul(W, Zo);
            float2 Xk  = f2add(Ze, V);
            float2 Xk2 = make_float2(Ze.x - V.x, V.y - Ze.y);
            float2 XSk  = scale_bin(Xk,  __half2float(g[tid + NT*(2*j)]));
            float2 XSk2 = scale_bin(Xk2, __half2float(g[tid + NT*(2*j + 1)]));
            repack_pair(s, XSk, XSk2, W, p, p2);
        }
        if (tid == 0) {
            float2 Z  = s[SW(2)];
            float2 XS = scale_bin(make_float2(Z.x, -Z.y), __half2float(g[2048]));
            s[SW(2)] = make_float2(XS.x, -XS.y);
        }
        __syncthreads();
    }

    fft_inv_rest(s, tw12, tw3t, tid);

    const float invn = 1.0f/2048.0f;
    {   // round A' (stride 256) in registers -> global write
        float2 d[8];
#pragma unroll
        for (int q = 0; q < 8; ++q) d[q] = s[SW(tid + 256*q)];
        r8i(d, tw12, tw3t, tid, 0);
        if (MODE == 0) {
            float2* caR = (float2*)(caF + (size_t)(bc*NFRAMES + f) * NFFT);
#pragma unroll
            for (int q = 0; q < 8; ++q) {
                int n = tid + 256*q;
                float2 w = w2c[n];
                caR[n] = make_float2(d[q].x*w.x*invn, d[q].y*w.y*invn);
            }
        } else if (MODE == 1) {
            unsigned* caH = (unsigned*)spx;      // overwrite spec row with fp16 ca
#pragma unroll
            for (int q = 0; q < 8; ++q) {
                int n = tid + 256*q;
                float2 w = w2c[n];
                caH[n] = packh2(d[q].x*w.x*invn, d[q].y*w.y*invn);
            }
        } else {
            float2* dst2 = (float2*)(out + (size_t)bc*NSAMP + (size_t)f*NHOP);
#pragma unroll
            for (int q = 0; q < 8; ++q) {
                int n = tid + 256*q;
                float2 w = w2c[n];
                float2 o = dst2[n];
                o.x += d[q].x * w.x * invn;
                o.y += d[q].y * w.y * invn;
                dst2[n] = o;
            }
        }
    }
}

// ---------------- kernel 4: overlap-add gather. CAH=0: fp32 ca; CAH=1: fp16 ca in spec ----------------
template<int CAH>
__global__ __launch_bounds__(NT) void k_ola(
    const float* __restrict__ caF, const uint2* __restrict__ spec,
    float* __restrict__ out)
{
    const int blk = blockIdx.x;
    const int bc = blk >> 9;          // 512 tiles of 1024 samples
    const int ti = blk & 511;
    const int tid = threadIdx.x;
    float4 acc = make_float4(0.f, 0.f, 0.f, 0.f);
    int flo = ti - 3; if (flo < 0) flo = 0;
    int fhi = ti; if (fhi > NFRAMES - 1) fhi = NFRAMES - 1;
    for (int f = flo; f <= fhi; ++f) {
        if (CAH) {
            const uint2* row = spec + (size_t)(bc*NFRAMES + f) * SPSTR;
            uint2 v = row[(ti - f)*256 + tid];
            float2 a = unpackh2(v.x), b = unpackh2(v.y);
            acc.x += a.x; acc.y += a.y; acc.z += b.x; acc.w += b.y;
        } else {
            const float4* row = (const float4*)(caF + (size_t)(bc*NFRAMES + f) * NFFT);
            float4 v = row[(ti - f)*256 + tid];
            acc.x += v.x; acc.y += v.y; acc.z += v.z; acc.w += v.w;
        }
    }
    ((float4*)(out + (size_t)bc*NSAMP))[ti*256 + tid] = acc;
}

extern "C" void kernel_launch(void* const* d_in, const int* in_sizes, int n_in,
                              void* d_out, int out_size, void* d_ws, size_t ws_size,
                              hipStream_t stream)
{
    const float* audio  = (const float*)d_in[0];
    const float* window = (const float*)d_in[1];
    const float* thr    = (const float*)d_in[2];
    const float* ratio  = (const float*)d_in[3];
    const float* makeup = (const float*)d_in[4];
    const float* knee   = (const float*)d_in[5];
    float* out = (float*)d_out;

    char* base = (char*)d_ws;
    float4* tw12 = (float4*)base;
    float2* tw3t = (float2*)(base + 8192);
    float4* wp   = (float4*)(base + 16384);
    float4* pa   = (float4*)(base + 32768);
    float4* pb   = (float4*)(base + 49152);
    float*  mkq  = (float*)(base + 65536);
    __half* gr   = (__half*)(base + WSHDR);
    const size_t grB = (size_t)NBC*NFRAMES*NK*sizeof(__half);            // 33.4 MB
    const size_t spB = (size_t)NBC*NFRAMES*SPSTR*sizeof(uint2);          // 66.8 MB
    const size_t caB = (size_t)NBC*NFRAMES*NFFT*sizeof(float);           // 133.5 MB
    const size_t needA = WSHDR + grB + caB + spB;    // fp32 ca, separate
    const size_t needB = WSHDR + grB + spB;          // fp16 ca in spec buffer

    dim3 blkd(NT);
    k_init<<<dim3((TWN + 1024 + NK + NT - 1)/NT), blkd, 0, stream>>>(
        thr, ratio, knee, makeup, tw12, tw3t, wp, pa, pb, mkq);

    if (ws_size >= needA) {
        float*  caF  = (float*)(base + WSHDR + grB);
        uint2*  spec = (uint2*)(base + WSHDR + grB + caB);
        k_fwd<1><<<dim3(NBC*NFRAMES), blkd, 0, stream>>>(
            audio, window, thr, ratio, knee, tw12, tw3t, wp, pa, pb, gr, spec);
        k_smooth<<<dim3((NBC*NK + STH - 1)/STH), dim3(STH), 0, stream>>>(gr, mkq);
        k_inv<0><<<dim3(NBC*NFRAMES), blkd, 0, stream>>>(
            audio, window, gr, tw12, tw3t, wp, spec, caF, out, 0, 0);
        k_ola<0><<<dim3(NBC*512), blkd, 0, stream>>>(caF, spec, out);
    } else if (ws_size >= needB) {
        uint2*  spec = (uint2*)(base + WSHDR + grB);
        k_fwd<1><<<dim3(NBC*NFRAMES), blkd, 0, stream>>>(
            audio, window, thr, ratio, knee, tw12, tw3t, wp, pa, pb, gr, spec);
        k_smooth<<<dim3((NBC*NK + STH - 1)/STH), dim3(STH), 0, stream>>>(gr, mkq);
        k_inv<1><<<dim3(NBC*NFRAMES), blkd, 0, stream>>>(
            audio, window, gr, tw12, tw3t, wp, spec, (float*)spec, out, 0, 0);
        k_ola<1><<<dim3(NBC*512), blkd, 0, stream>>>((const float*)spec, spec, out);
    } else {
        hipMemsetAsync(d_out, 0, (size_t)out_size*sizeof(float), stream);
        uint2* spec = (uint2*)(base + WSHDR + grB);   // unused in MODE 2
        k_fwd<0><<<dim3(NBC*NFRAMES), blkd, 0, stream>>>(
            audio, window, thr, ratio, knee, tw12, tw3t, wp, pa, pb, gr, spec);
        k_smooth<<<dim3((NBC*NK + STH - 1)/STH), dim3(STH), 0, stream>>>(gr, mkq);
        for (int pass = 0; pass < 4; ++pass) {
            int nfp = (NFRAMES - pass + 3) / 4;
            k_inv<2><<<dim3(NBC*nfp), blkd, 0, stream>>>(
                audio, window, gr, tw12, tw3t, wp, spec, (float*)spec, out, pass, nfp);
        }
    }
}

// Round 10
// 211.463 us; speedup vs baseline: 1.5139x; 1.5139x over previous
//
#include <hip/hip_runtime.h>
#include <hip/hip_fp16.h>

#define NFFT     4096
#define NC       2048      // complex FFT length (real-packed)
#define NHOP     1024
#define NK       2049
#define NBC      16
#define NSAMP    524288
#define NFRAMES  509
#define NFR2     520       // padded frame rows for branch-free smooth prefetch
#define NT       256
#define STH      64        // k_smooth block size
#define SPSTR    1025      // spec row stride in uint2 (1024 pairs + bin1024)
#define RSTR     1025      // gr row stride in uint (1024 pairs + bin1024)

#define A_COEFF 0.0022650046943f     // 1 - exp(-1/441)
#define R_COEFF 0.00022673165872f    // 1 - exp(-1/4410)
#define DB2LIN_LOG2 0.16609640474436812f  // log2(10)/20
#define DB_LOG2     6.02059991327962390f  // 20*log10(2)
#define PI_D 3.14159265358979323846264338327950288

// LDS swizzle: ~2-way max at every FFT stage
#define SW(e) ((e) + 7*((e)>>5))
#define SWSZ 2489      // SW(2047)+1  -> 19912 B LDS = 8 blocks/CU
#define TWN  292       // radix-8 stage tables: 256(A) + 32(B) + 4(C)
// ws header (bytes): tw12@0, tw3t@8192, wp@16384, pa@32768, pb@49152, mkq2@65536
#define WSHDR 131072

__device__ __forceinline__ float2 cmul(float2 a, float2 b){
    return make_float2(a.x*b.x - a.y*b.y, a.x*b.y + a.y*b.x);
}
__device__ __forceinline__ float2 cmulc(float2 a, float2 b){   // a * conj(b)
    return make_float2(a.x*b.x + a.y*b.y, a.y*b.x - a.x*b.y);
}
__device__ __forceinline__ float2 f2add(float2 a, float2 b){ return make_float2(a.x+b.x, a.y+b.y); }
__device__ __forceinline__ float2 f2sub(float2 a, float2 b){ return make_float2(a.x-b.x, a.y-b.y); }

union HU { unsigned u; __half2 h; };
__device__ __forceinline__ unsigned packh2(float a, float b){
    HU x; x.h = __floats2half2_rn(a, b); return x.u;
}
__device__ __forceinline__ float2 unpackh2(unsigned v){
    HU x; x.u = v; float2 r = __half22float2(x.h); return r;
}

#define RSQRT2 0.70710678118654752f

// mixed-radix (8,8,8,4) digit scramble (host-side tables only)
__device__ __forceinline__ int revm(int p){
    return (p>>8) + 8*((p>>5)&7) + 64*((p>>2)&7) + 512*(p&3);
}
__device__ __forceinline__ int pmap(int k){
    return ((k&7)<<8) | (((k>>3)&7)<<5) | (((k>>6)&7)<<2) | ((k>>9)&3);
}
__device__ __forceinline__ int p_of_m(int m){ return ((m>>1)<<2) | (m&1); }

// ---------------- radix-8 forward core: butterfly then twiddle, in place ----------------
__device__ __forceinline__ void r8f(float2* d, const float4* __restrict__ tw12,
                                    const float2* __restrict__ tw3t, int n, int toff){
    float2 EA0=f2add(d[0],d[4]), EA1=f2sub(d[0],d[4]);
    float2 EB0=f2add(d[2],d[6]), EB1=f2sub(d[2],d[6]);
    float2 OA0=f2add(d[1],d[5]), OA1=f2sub(d[1],d[5]);
    float2 OB0=f2add(d[3],d[7]), OB1=f2sub(d[3],d[7]);
    float2 E0=f2add(EA0,EB0), E2=f2sub(EA0,EB0);
    float2 E1=make_float2(EA1.x+EB1.y, EA1.y-EB1.x);   // EA1 - i*EB1
    float2 E3=make_float2(EA1.x-EB1.y, EA1.y+EB1.x);   // EA1 + i*EB1
    float2 O0=f2add(OA0,OB0), O2=f2sub(OA0,OB0);
    float2 O1=make_float2(OA1.x+OB1.y, OA1.y-OB1.x);
    float2 O3=make_float2(OA1.x-OB1.y, OA1.y+OB1.x);
    const float c = RSQRT2;
    float2 t1=make_float2(c*(O1.x+O1.y), c*(O1.y-O1.x));   // w8^1 * O1
    float2 u2=make_float2(O2.y, -O2.x);                    // -i * O2
    float2 v3=make_float2(c*(O3.y-O3.x), -c*(O3.x+O3.y));  // w8^3 * O3
    float4 w12 = tw12[toff + n];
    float2 w1 = make_float2(w12.x, w12.y), w2 = make_float2(w12.z, w12.w);
    float2 w3 = tw3t[toff + n];
    float2 w4 = cmul(w2,w2), w5 = cmul(w2,w3), w6 = cmul(w3,w3), w7 = cmul(w3,w4);
    d[0] = f2add(E0,O0);
    d[1] = cmul(f2add(E1,t1), w1);
    d[2] = cmul(f2add(E2,u2), w2);
    d[3] = cmul(f2add(E3,v3), w3);
    d[4] = cmul(f2sub(E0,O0), w4);
    d[5] = cmul(f2sub(E1,t1), w5);
    d[6] = cmul(f2sub(E2,u2), w6);
    d[7] = cmul(f2sub(E3,v3), w7);
}

// ---------------- radix-8 inverse core: conj-twiddle then inverse butterfly ----------------
__device__ __forceinline__ void r8i(float2* d, const float4* __restrict__ tw12,
                                    const float2* __restrict__ tw3t, int n, int toff){
    float4 w12 = tw12[toff + n];
    float2 w1 = make_float2(w12.x, w12.y), w2 = make_float2(w12.z, w12.w);
    float2 w3 = tw3t[toff + n];
    float2 w4 = cmul(w2,w2), w5 = cmul(w2,w3), w6 = cmul(w3,w3), w7 = cmul(w3,w4);
    d[1]=cmulc(d[1],w1); d[2]=cmulc(d[2],w2); d[3]=cmulc(d[3],w3); d[4]=cmulc(d[4],w4);
    d[5]=cmulc(d[5],w5); d[6]=cmulc(d[6],w6); d[7]=cmulc(d[7],w7);
    float2 EA0=f2add(d[0],d[4]), EA1=f2sub(d[0],d[4]);
    float2 EB0=f2add(d[2],d[6]), EB1=f2sub(d[2],d[6]);
    float2 OA0=f2add(d[1],d[5]), OA1=f2sub(d[1],d[5]);
    float2 OB0=f2add(d[3],d[7]), OB1=f2sub(d[3],d[7]);
    float2 E0=f2add(EA0,EB0), E2=f2sub(EA0,EB0);
    float2 E1=make_float2(EA1.x-EB1.y, EA1.y+EB1.x);   // EA1 + i*EB1
    float2 E3=make_float2(EA1.x+EB1.y, EA1.y-EB1.x);
    float2 O0=f2add(OA0,OB0), O2=f2sub(OA0,OB0);
    float2 O1=make_float2(OA1.x-OB1.y, OA1.y+OB1.x);
    float2 O3=make_float2(OA1.x+OB1.y, OA1.y-OB1.x);
    const float c = RSQRT2;
    float2 t1=make_float2(c*(O1.x-O1.y), c*(O1.y+O1.x));    // conj(w8)*O1
    float2 u2=make_float2(-O2.y, O2.x);                     // +i*O2
    float2 v3=make_float2(-c*(O3.x+O3.y), c*(O3.x-O3.y));   // conj(w8^3)*O3
    d[0] = f2add(E0,O0);
    d[1] = f2add(E1,t1);
    d[2] = f2add(E2,u2);
    d[3] = f2add(E3,v3);
    d[4] = f2sub(E0,O0);
    d[5] = f2sub(E1,t1);
    d[6] = f2sub(E2,u2);
    d[7] = f2sub(E3,v3);
}

// rounds B, C, D of forward FFT (round A done by caller in registers)
__device__ __forceinline__ void fft_fwd_rest(float2* s, const float4* __restrict__ tw12,
                                             const float2* __restrict__ tw3t, int tid){
    __syncthreads();
    {   // round B, stride 32
        int base = (tid>>5)*256 + (tid&31);
        float2 d[8];
#pragma unroll
        for (int q = 0; q < 8; ++q) d[q] = s[SW(base + 32*q)];
        r8f(d, tw12, tw3t, tid&31, 256);
#pragma unroll
        for (int q = 0; q < 8; ++q) s[SW(base + 32*q)] = d[q];
    }
    __syncthreads();
    {   // round C, stride 4
        int base = (tid>>2)*32 + (tid&3);
        float2 d[8];
#pragma unroll
        for (int q = 0; q < 8; ++q) d[q] = s[SW(base + 4*q)];
        r8f(d, tw12, tw3t, tid&3, 288);
#pragma unroll
        for (int q = 0; q < 8; ++q) s[SW(base + 4*q)] = d[q];
    }
    __syncthreads();
    {   // round D: radix-4 span-1, trivial twiddle, contiguous 8/thread
        int g8 = 8*tid;
#pragma unroll
        for (int h = 0; h < 2; ++h) {
            int b4 = g8 + 4*h;
            float2 x0=s[SW(b4)], x1=s[SW(b4+1)], x2=s[SW(b4+2)], x3=s[SW(b4+3)];
            float2 A0=f2add(x0,x2), A1=f2sub(x0,x2);
            float2 B0=f2add(x1,x3), B1=f2sub(x1,x3);
            s[SW(b4)]   = f2add(A0,B0);
            s[SW(b4+1)] = make_float2(A1.x + B1.y, A1.y - B1.x);  // A1 - i*B1
            s[SW(b4+2)] = f2sub(A0,B0);
            s[SW(b4+3)] = make_float2(A1.x - B1.y, A1.y + B1.x);  // A1 + i*B1
        }
    }
    __syncthreads();
}

// rounds D', C', B' of inverse FFT; caller does round A' in registers afterwards
__device__ __forceinline__ void fft_inv_rest(float2* s, const float4* __restrict__ tw12,
                                             const float2* __restrict__ tw3t, int tid){
    {   // radix-4 span-1 inverse
        int g8 = 8*tid;
#pragma unroll
        for (int h = 0; h < 2; ++h) {
            int b4 = g8 + 4*h;
            float2 z0=s[SW(b4)], z1=s[SW(b4+1)], z2=s[SW(b4+2)], z3=s[SW(b4+3)];
            float2 A0=f2add(z0,z2), A1=f2sub(z0,z2);
            float2 B0=f2add(z1,z3), B1=f2sub(z1,z3);
            s[SW(b4)]   = f2add(A0,B0);
            s[SW(b4+1)] = make_float2(A1.x - B1.y, A1.y + B1.x);  // A1 + i*B1
            s[SW(b4+2)] = f2sub(A0,B0);
            s[SW(b4+3)] = make_float2(A1.x + B1.y, A1.y - B1.x);  // A1 - i*B1
        }
    }
    __syncthreads();
    {   // C' stride 4
        int base = (tid>>2)*32 + (tid&3);
        float2 d[8];
#pragma unroll
        for (int q = 0; q < 8; ++q) d[q] = s[SW(base + 4*q)];
        r8i(d, tw12, tw3t, tid&3, 288);
#pragma unroll
        for (int q = 0; q < 8; ++q) s[SW(base + 4*q)] = d[q];
    }
    __syncthreads();
    {   // B' stride 32
        int base = (tid>>5)*256 + (tid&31);
        float2 d[8];
#pragma unroll
        for (int q = 0; q < 8; ++q) d[q] = s[SW(base + 32*q)];
        r8i(d, tw12, tw3t, tid&31, 256);
#pragma unroll
        for (int q = 0; q < 8; ++q) s[SW(base + 32*q)] = d[q];
    }
    __syncthreads();
}

// q = {th, ks, 1/kw, slope}; input is |X|^2
__device__ __forceinline__ float gr_of2(float a2, float4 q){
    float mag_db = 0.5f * DB_LOG2 * log2f(fmaxf(a2, 1e-16f));
    float over = mag_db - q.x;
    float hard = (mag_db < q.x) ? 0.0f : over*q.w;
    float kf = fminf(fmaxf((mag_db - q.y)*q.z, 0.0f), 1.0f);
    float kneeg = kf*kf*over*q.w;
    float ke = 2.0f*q.x - q.y;
    return (mag_db >= q.y && mag_db <= ke) ? kneeg : hard;
}

__device__ __forceinline__ float2 scale_bin(float2 X, float g){
    float a2 = X.x*X.x + X.y*X.y;
    if (a2 >= 1e-16f) return make_float2(g*X.x, g*X.y);
    if (a2 > 0.f)  { float sc = g*1e-8f*rsqrtf(a2); return make_float2(sc*X.x, sc*X.y); }
    return make_float2(g*1e-8f, 0.f);
}

// ---------------- init: twiddles + pair table {W, p, p2} + params + makeup pairs ----------------
__global__ __launch_bounds__(NT) void k_init(
    const float* __restrict__ thr, const float* __restrict__ ratio,
    const float* __restrict__ knee, const float* __restrict__ makeup,
    float4* __restrict__ tw12, float2* __restrict__ tw3t,
    float4* __restrict__ wp, float4* __restrict__ pa, float4* __restrict__ pb,
    float2* __restrict__ mkq2)
{
    int i = blockIdx.x*NT + threadIdx.x;
    if (i < TWN) {
        int n, len;
        if (i < 256)      { n = i;       len = 2048; }
        else if (i < 288) { n = i - 256; len = 256;  }
        else              { n = i - 288; len = 32;   }
        double ang = -2.0*PI_D*(double)n/(double)len;
        tw12[i] = make_float4((float)cos(ang), (float)sin(ang),
                              (float)cos(2.0*ang), (float)sin(2.0*ang));
        tw3t[i] = make_float2((float)cos(3.0*ang), (float)sin(3.0*ang));
    } else if (i < TWN + 1024) {
        int m = i - TWN;
        int p  = p_of_m(m);
        int k  = revm(p);
        int k2 = (k == 0) ? 2048 : 2048 - k;
        int p2 = pmap((2048 - k) & 2047);
        double ang = -PI_D*(double)k/2048.0;   // E(k/4096)
        wp[m] = make_float4((float)cos(ang), (float)sin(ang),
                            __int_as_float(p), __int_as_float(p2));
        float th = thr[k], ra = ratio[k], kw = knee[k];
        pa[m] = make_float4(th, th - 0.5f*kw, 1.0f/kw, 1.0f - 1.0f/ra);
        th = thr[k2]; ra = ratio[k2]; kw = knee[k2];
        pb[m] = make_float4(th, th - 0.5f*kw, 1.0f/kw, 1.0f - 1.0f/ra);
        mkq2[m] = make_float2(exp2f(makeup[k]  * DB2LIN_LOG2),
                              exp2f(makeup[k2] * DB2LIN_LOG2));
    } else if (i == TWN + 1024) {
        mkq2[1024] = make_float2(exp2f(makeup[1024] * DB2LIN_LOG2), 1.0f);
    }
}

// ---------------- kernel 1: STFT (round A fused with load); fp16 spec pairs + packed gr ----------------
template<int STORESPEC>
__global__ __launch_bounds__(NT, 8) void k_fwd(
    const float* __restrict__ audio, const float* __restrict__ window,
    const float* __restrict__ thr, const float* __restrict__ ratio,
    const float* __restrict__ knee,
    const float4* __restrict__ tw12, const float2* __restrict__ tw3t,
    const float4* __restrict__ wp, const float4* __restrict__ pa,
    const float4* __restrict__ pb,
    unsigned* __restrict__ gr, uint2* __restrict__ spec)
{
    __shared__ float2 s[SWSZ];
    const int tid = threadIdx.x;
    const int blk = blockIdx.x;
    const int bc  = blk / NFRAMES;
    const int f   = blk - bc*NFRAMES;

    const float2* a2c = (const float2*)(audio + (size_t)bc*NSAMP + (size_t)f*NHOP);
    const float2* w2c = (const float2*)window;
    {   // fused load + round A (stride 256), registers only
        float2 d[8];
#pragma unroll
        for (int q = 0; q < 8; ++q) {
            int n = tid + 256*q;
            float2 u = a2c[n], w = w2c[n];
            d[q] = make_float2(u.x*w.x, u.y*w.y);     // z[n] = x[2n]w + i x[2n+1]w
        }
        r8f(d, tw12, tw3t, tid, 0);
#pragma unroll
        for (int q = 0; q < 8; ++q) s[SW(tid + 256*q)] = d[q];
    }
    fft_fwd_rest(s, tw12, tw3t, tid);

    unsigned* grow = gr + (size_t)(bc*NFR2 + f) * RSTR;
    uint2* spx = spec + (size_t)(bc*NFRAMES + f) * SPSTR;
#pragma unroll
    for (int j = 0; j < 4; ++j) {
        int m  = tid + NT*j;
        float4 wpv = wp[m];
        int p  = __float_as_int(wpv.z);
        int p2 = __float_as_int(wpv.w);
        float2 Zk  = s[SW(p)];
        float2 Zk2 = s[SW(p2)];
        float2 Ze = make_float2(0.5f*(Zk.x + Zk2.x), 0.5f*(Zk.y - Zk2.y));
        float2 Zo = make_float2(0.5f*(Zk.y + Zk2.y), -0.5f*(Zk.x - Zk2.x));
        float2 W  = make_float2(wpv.x, wpv.y);
        float2 V  = cmul(W, Zo);
        float2 Xk  = f2add(Ze, V);                              // X[k]
        float2 Xk2 = make_float2(Ze.x - V.x, V.y - Ze.y);       // X[2048-k]
        if (STORESPEC)
            spx[m] = make_uint2(packh2(Xk.x, Xk.y), packh2(Xk2.x, Xk2.y));
        grow[m] = packh2(gr_of2(Xk.x*Xk.x + Xk.y*Xk.y,   pa[m]),
                         gr_of2(Xk2.x*Xk2.x + Xk2.y*Xk2.y, pb[m]));
    }
    if (tid == 0) {   // self-paired bin 1024 at slot pmap(1024)=2: X = conj(Z)
        float2 Z = s[SW(2)];
        if (STORESPEC) spx[1024] = make_uint2(packh2(Z.x, -Z.y), 0u);
        float th = thr[1024], ra = ratio[1024], kw = knee[1024];
        float4 q = make_float4(th, th - 0.5f*kw, 1.0f/kw, 1.0f - 1.0f/ra);
        grow[1024] = packh2(gr_of2(Z.x*Z.x + Z.y*Z.y, q), 0.f);
    }
}

// ---------------- kernel 2: attack/release scan; two env chains per thread, uint I/O ----------------
__global__ __launch_bounds__(STH) void k_smooth(
    unsigned* __restrict__ gr, const float2* __restrict__ mkq2)
{
    int gid = blockIdx.x*STH + threadIdx.x;
    if (gid >= NBC*RSTR) return;
    int bc = gid / RSTR;
    int m  = gid - bc*RSTR;
    float2 mk = mkq2[m];
    unsigned* p = gr + (size_t)bc*NFR2*RSTR + m;

    float env1 = 0.f, env2 = 0.f;
    unsigned curv[8], nxtv[8];
#pragma unroll
    for (int d = 0; d < 8; ++d) curv[d] = p[(size_t)d*RSTR];
    for (int c = 0; c < 512; c += 8) {
        if (c < 504) {
#pragma unroll
            for (int d = 0; d < 8; ++d) nxtv[d] = p[(size_t)(c+8+d)*RSTR];
        }
        float t1[8], t2[8];
#pragma unroll
        for (int d = 0; d < 8; ++d) {
            float2 gdb = unpackh2(curv[d]);
            t1[d] = exp2f(gdb.x * -DB2LIN_LOG2);     // tgt, indep of env
            t2[d] = exp2f(gdb.y * -DB2LIN_LOG2);
        }
#pragma unroll
        for (int d = 0; d < 8; ++d) {
            float c1 = (t1[d] < env1) ? A_COEFF : R_COEFF;
            env1 = fmaf(c1, t1[d] - env1, env1);
            float c2 = (t2[d] < env2) ? A_COEFF : R_COEFF;
            env2 = fmaf(c2, t2[d] - env2, env2);
            curv[d] = packh2(fmaxf(env1, 1e-8f) * mk.x,
                             fmaxf(env2, 1e-8f) * mk.y);
        }
#pragma unroll
        for (int d = 0; d < 8; ++d) p[(size_t)(c+d)*RSTR] = curv[d];
#pragma unroll
        for (int d = 0; d < 8; ++d) curv[d] = nxtv[d];
    }
}

// repack scaled pair (XSk, XSk2) of bin k into packed-spectrum LDS slots (p, p2)
__device__ __forceinline__ void repack_pair(float2* s, float2 XSk, float2 XSk2,
                                            float2 W, int p, int p2){
    // Z'[k] = E + i*conj(W)*P ; Z'[k2] = conj(E) + i*W*conj(P)
    float2 E = make_float2(0.5f*(XSk.x + XSk2.x), 0.5f*(XSk.y - XSk2.y));
    float2 P = make_float2(0.5f*(XSk.x - XSk2.x), 0.5f*(XSk.y + XSk2.y));
    float2 Wc = make_float2(W.x, -W.y);
    float2 Q  = cmul(Wc, P);
    float2 Pc = make_float2(P.x, -P.y);
    float2 R  = cmul(W, Pc);
    s[SW(p)]  = make_float2(E.x - Q.y, E.y + Q.x);
    s[SW(p2)] = make_float2(E.x - R.y, R.x - E.y);
}

// MODE 0: spec -> scale -> ifft -> ca fp32 (separate buffer)
// MODE 1: spec -> scale -> ifft -> ca fp16 (in place over spec row)
// MODE 2: fallback — recompute fwd FFT from audio, scale, ifft, RMW out (4 passes)
template<int MODE>
__global__ __launch_bounds__(NT, 8) void k_inv(
    const float* __restrict__ audio, const float* __restrict__ window,
    const unsigned* __restrict__ gains,
    const float4* __restrict__ tw12, const float2* __restrict__ tw3t,
    const float4* __restrict__ wp,
    uint2* __restrict__ spec, float* __restrict__ caF,
    float* __restrict__ out, int pass, int nfp)
{
    __shared__ float2 s[SWSZ];
    const int tid = threadIdx.x;
    const int blk = blockIdx.x;
    int bc, f;
    if (MODE != 2) { bc = blk / NFRAMES; f = blk - bc*NFRAMES; }
    else           { bc = blk / nfp;     f = pass + 4*(blk - bc*nfp); }

    const float2* w2c = (const float2*)window;
    const unsigned* grow = gains + (size_t)(bc*NFR2 + f) * RSTR;
    uint2* spx = spec + (size_t)(bc*NFRAMES + f) * SPSTR;

    if (MODE != 2) {
        // scale + repack directly from fp16 spec pairs (no FFT, no unpack)
#pragma unroll
        for (int j = 0; j < 4; ++j) {
            int m = tid + NT*j;
            uint2 v = spx[m];
            float4 wpv = wp[m];
            float2 gg = unpackh2(grow[m]);
            float2 XSk  = scale_bin(unpackh2(v.x), gg.x);
            float2 XSk2 = scale_bin(unpackh2(v.y), gg.y);
            repack_pair(s, XSk, XSk2, make_float2(wpv.x, wpv.y),
                        __float_as_int(wpv.z), __float_as_int(wpv.w));
        }
        if (tid == 0) {
            uint2 v = spx[1024];
            float2 gg = unpackh2(grow[1024]);
            float2 XS = scale_bin(unpackh2(v.x), gg.x);
            s[SW(2)] = make_float2(XS.x, -XS.y);     // Z' = conj(XS)
        }
        __syncthreads();
    } else {
        {   // fused load + forward round A
            const float2* a2c = (const float2*)(audio + (size_t)bc*NSAMP + (size_t)f*NHOP);
            float2 d[8];
#pragma unroll
            for (int q = 0; q < 8; ++q) {
                int n = tid + 256*q;
                float2 u = a2c[n], w = w2c[n];
                d[q] = make_float2(u.x*w.x, u.y*w.y);
            }
            r8f(d, tw12, tw3t, tid, 0);
#pragma unroll
            for (int q = 0; q < 8; ++q) s[SW(tid + 256*q)] = d[q];
        }
        fft_fwd_rest(s, tw12, tw3t, tid);
        // unpack + scale + repack in place
#pragma unroll
        for (int j = 0; j < 4; ++j) {
            int m = tid + NT*j;
            float4 wpv = wp[m];
            int p  = __float_as_int(wpv.z);
            int p2 = __float_as_int(wpv.w);
            float2 Zk  = s[SW(p)];
            float2 Zk2 = s[SW(p2)];
            float2 Ze = make_float2(0.5f*(Zk.x + Zk2.x), 0.5f*(Zk.y - Zk2.y));
            float2 Zo = make_float2(0.5f*(Zk.y + Zk2.y), -0.5f*(Zk.x - Zk2.x));
            float2 W  = make_float2(wpv.x, wpv.y);
            float2 V  = cmul(W, Zo);
            float2 Xk  = f2add(Ze, V);
            float2 Xk2 = make_float2(Ze.x - V.x, V.y - Ze.y);
            float2 gg = unpackh2(grow[m]);
            float2 XSk  = scale_bin(Xk,  gg.x);
            float2 XSk2 = scale_bin(Xk2, gg.y);
            repack_pair(s, XSk, XSk2, W, p, p2);
        }
        if (tid == 0) {
            float2 Z  = s[SW(2)];
            float2 gg = unpackh2(grow[1024]);
            float2 XS = scale_bin(make_float2(Z.x, -Z.y), gg.x);
            s[SW(2)] = make_float2(XS.x, -XS.y);
        }
        __syncthreads();
    }

    fft_inv_rest(s, tw12, tw3t, tid);

    const float invn = 1.0f/2048.0f;
    {   // round A' (stride 256) in registers -> global write
        float2 d[8];
#pragma unroll
        for (int q = 0; q < 8; ++q) d[q] = s[SW(tid + 256*q)];
        r8i(d, tw12, tw3t, tid, 0);
        if (MODE == 0) {
            float2* caR = (float2*)(caF + (size_t)(bc*NFRAMES + f) * NFFT);
#pragma unroll
            for (int q = 0; q < 8; ++q) {
                int n = tid + 256*q;
                float2 w = w2c[n];
                caR[n] = make_float2(d[q].x*w.x*invn, d[q].y*w.y*invn);
            }
        } else if (MODE == 1) {
            unsigned* caH = (unsigned*)spx;      // overwrite spec row with fp16 ca
#pragma unroll
            for (int q = 0; q < 8; ++q) {
                int n = tid + 256*q;
                float2 w = w2c[n];
                caH[n] = packh2(d[q].x*w.x*invn, d[q].y*w.y*invn);
            }
        } else {
            float2* dst2 = (float2*)(out + (size_t)bc*NSAMP + (size_t)f*NHOP);
#pragma unroll
            for (int q = 0; q < 8; ++q) {
                int n = tid + 256*q;
                float2 w = w2c[n];
                float2 o = dst2[n];
                o.x += d[q].x * w.x * invn;
                o.y += d[q].y * w.y * invn;
                dst2[n] = o;
            }
        }
    }
}

// ---------------- kernel 4: overlap-add gather. CAH=0: fp32 ca; CAH=1: fp16 ca in spec ----------------
template<int CAH>
__global__ __launch_bounds__(NT) void k_ola(
    const float* __restrict__ caF, const uint2* __restrict__ spec,
    float* __restrict__ out)
{
    const int blk = blockIdx.x;
    const int bc = blk >> 9;          // 512 tiles of 1024 samples
    const int ti = blk & 511;
    const int tid = threadIdx.x;
    float4 acc = make_float4(0.f, 0.f, 0.f, 0.f);
    int flo = ti - 3; if (flo < 0) flo = 0;
    int fhi = ti; if (fhi > NFRAMES - 1) fhi = NFRAMES - 1;
    for (int f = flo; f <= fhi; ++f) {
        if (CAH) {
            const uint2* row = spec + (size_t)(bc*NFRAMES + f) * SPSTR;
            uint2 v = row[(ti - f)*256 + tid];
            float2 a = unpackh2(v.x), b = unpackh2(v.y);
            acc.x += a.x; acc.y += a.y; acc.z += b.x; acc.w += b.y;
        } else {
            const float4* row = (const float4*)(caF + (size_t)(bc*NFRAMES + f) * NFFT);
            float4 v = row[(ti - f)*256 + tid];
            acc.x += v.x; acc.y += v.y; acc.z += v.z; acc.w += v.w;
        }
    }
    ((float4*)(out + (size_t)bc*NSAMP))[ti*256 + tid] = acc;
}

extern "C" void kernel_launch(void* const* d_in, const int* in_sizes, int n_in,
                              void* d_out, int out_size, void* d_ws, size_t ws_size,
                              hipStream_t stream)
{
    const float* audio  = (const float*)d_in[0];
    const float* window = (const float*)d_in[1];
    const float* thr    = (const float*)d_in[2];
    const float* ratio  = (const float*)d_in[3];
    const float* makeup = (const float*)d_in[4];
    const float* knee   = (const float*)d_in[5];
    float* out = (float*)d_out;

    char* base = (char*)d_ws;
    float4* tw12 = (float4*)base;
    float2* tw3t = (float2*)(base + 8192);
    float4* wp   = (float4*)(base + 16384);
    float4* pa   = (float4*)(base + 32768);
    float4* pb   = (float4*)(base + 49152);
    float2* mkq2 = (float2*)(base + 65536);
    unsigned* gr = (unsigned*)(base + WSHDR);
    const size_t grB = (size_t)NBC*NFR2*RSTR*sizeof(unsigned);           // 34.1 MB
    const size_t spB = (size_t)NBC*NFRAMES*SPSTR*sizeof(uint2);          // 66.8 MB
    const size_t caB = (size_t)NBC*NFRAMES*NFFT*sizeof(float);           // 133.5 MB
    const size_t needA = WSHDR + grB + caB + spB;    // fp32 ca, separate
    const size_t needB = WSHDR + grB + spB;          // fp16 ca in spec buffer

    dim3 blkd(NT);
    k_init<<<dim3((TWN + 1025 + NT - 1)/NT), blkd, 0, stream>>>(
        thr, ratio, knee, makeup, tw12, tw3t, wp, pa, pb, mkq2);

    int sblocks = (NBC*RSTR + STH - 1)/STH;
    if (ws_size >= needA) {
        float*  caF  = (float*)(base + WSHDR + grB);
        uint2*  spec = (uint2*)(base + WSHDR + grB + caB);
        k_fwd<1><<<dim3(NBC*NFRAMES), blkd, 0, stream>>>(
            audio, window, thr, ratio, knee, tw12, tw3t, wp, pa, pb, gr, spec);
        k_smooth<<<dim3(sblocks), dim3(STH), 0, stream>>>(gr, mkq2);
        k_inv<0><<<dim3(NBC*NFRAMES), blkd, 0, stream>>>(
            audio, window, gr, tw12, tw3t, wp, spec, caF, out, 0, 0);
        k_ola<0><<<dim3(NBC*512), blkd, 0, stream>>>(caF, spec, out);
    } else if (ws_size >= needB) {
        uint2*  spec = (uint2*)(base + WSHDR + grB);
        k_fwd<1><<<dim3(NBC*NFRAMES), blkd, 0, stream>>>(
            audio, window, thr, ratio, knee, tw12, tw3t, wp, pa, pb, gr, spec);
        k_smooth<<<dim3(sblocks), dim3(STH), 0, stream>>>(gr, mkq2);
        k_inv<1><<<dim3(NBC*NFRAMES), blkd, 0, stream>>>(
            audio, window, gr, tw12, tw3t, wp, spec, (float*)spec, out, 0, 0);
        k_ola<1><<<dim3(NBC*512), blkd, 0, stream>>>((const float*)spec, spec, out);
    } else {
        hipMemsetAsync(d_out, 0, (size_t)out_size*sizeof(float), stream);
        uint2* spec = (uint2*)(base + WSHDR + grB);   // unused in MODE 2
        k_fwd<0><<<dim3(NBC*NFRAMES), blkd, 0, stream>>>(
            audio, window, thr, ratio, knee, tw12, tw3t, wp, pa, pb, gr, spec);
        k_smooth<<<dim3(sblocks), dim3(STH), 0, stream>>>(gr, mkq2);
        for (int pass = 0; pass < 4; ++pass) {
            int nfp = (NFRAMES - pass + 3) / 4;
            k_inv<2><<<dim3(NBC*nfp), blkd, 0, stream>>>(
                audio, window, gr, tw12, tw3t, wp, spec, (float*)spec, out, pass, nfp);
        }
    }
}

// Round 11
// 184.230 us; speedup vs baseline: 1.7377x; 1.1478x over previous
//
#include <hip/hip_runtime.h>
#include <hip/hip_fp16.h>

#define NFFT     4096
#define NC       2048      // complex FFT length (real-packed)
#define NHOP     1024
#define NK       2049
#define NBC      16
#define NSAMP    524288
#define NFRAMES  509
#define NFR2     520       // padded frame rows for branch-free smooth prefetch
#define NT       256
#define STH      64        // k_smooth block size
#define SPSTR    1025      // spec row stride in uint2 (1024 pairs + bin1024)
#define RSTR     1025      // gr row stride in uint (1024 pairs + bin1024)

#define A_COEFF 0.0022650046943f     // 1 - exp(-1/441)
#define R_COEFF 0.00022673165872f    // 1 - exp(-1/4410)
#define DB2LIN_LOG2 0.16609640474436812f  // log2(10)/20
#define DB_LOG2     6.02059991327962390f  // 20*log10(2)
#define PI_D 3.14159265358979323846264338327950288

// LDS swizzle: ~2-way max at every FFT stage
#define SW(e) ((e) + 7*((e)>>5))
#define SWSZ 2489      // SW(2047)+1  -> 19912 B LDS = 8 blocks/CU
#define TWN  292       // radix-8 stage tables: 256(A) + 32(B) + 4(C)
// ws header (bytes): tw12@0, tw3t@8192, wp@16384, pa@32768, pb@49152, mkq2@65536
#define WSHDR 131072

// packed-f32 complex: lane0=re, lane1=im -> v_pk_* dual-issue on gfx950
typedef float cplx __attribute__((ext_vector_type(2)));
#define C2(a,b) ((cplx){(float)(a), (float)(b)})

__device__ __forceinline__ cplx cmul(cplx a, cplx b){
    cplx p = C2(a.x, a.x) * b;                 // (ax*br, ax*bi)
    cplx q = C2(a.y, a.y) * C2(b.y, b.x);      // (ay*bi, ay*br)
    return C2(p.x - q.x, p.y + q.y);           // pk_add with neg_lo
}
__device__ __forceinline__ cplx cmulc(cplx a, cplx b){   // a * conj(b)
    cplx p = C2(a.x, a.x) * b;
    cplx q = C2(a.y, a.y) * C2(b.y, b.x);
    return C2(p.x + q.x, q.y - p.y);
}

union HU { unsigned u; __half2 h; };
__device__ __forceinline__ unsigned packh2(float a, float b){
    HU x; x.h = __floats2half2_rn(a, b); return x.u;
}
__device__ __forceinline__ cplx unpackh2(unsigned v){
    HU x; x.u = v; float2 r = __half22float2(x.h); return C2(r.x, r.y);
}

#define RSQRT2 0.70710678118654752f

// mixed-radix (8,8,8,4) digit scramble (host-side tables only)
__device__ __forceinline__ int revm(int p){
    return (p>>8) + 8*((p>>5)&7) + 64*((p>>2)&7) + 512*(p&3);
}
__device__ __forceinline__ int pmap(int k){
    return ((k&7)<<8) | (((k>>3)&7)<<5) | (((k>>6)&7)<<2) | ((k>>9)&3);
}
__device__ __forceinline__ int p_of_m(int m){ return ((m>>1)<<2) | (m&1); }

// ---------------- radix-8 forward core: butterfly then twiddle, in place ----------------
__device__ __forceinline__ void r8f(cplx* d, const float4* __restrict__ tw12,
                                    const float2* __restrict__ tw3t, int n, int toff){
    cplx EA0=d[0]+d[4], EA1=d[0]-d[4];
    cplx EB0=d[2]+d[6], EB1=d[2]-d[6];
    cplx OA0=d[1]+d[5], OA1=d[1]-d[5];
    cplx OB0=d[3]+d[7], OB1=d[3]-d[7];
    cplx E0=EA0+EB0, E2=EA0-EB0;
    cplx E1=C2(EA1.x+EB1.y, EA1.y-EB1.x);   // EA1 - i*EB1
    cplx E3=C2(EA1.x-EB1.y, EA1.y+EB1.x);   // EA1 + i*EB1
    cplx O0=OA0+OB0, O2=OA0-OB0;
    cplx O1=C2(OA1.x+OB1.y, OA1.y-OB1.x);
    cplx O3=C2(OA1.x-OB1.y, OA1.y+OB1.x);
    const float c = RSQRT2;
    cplx t1=C2(c*(O1.x+O1.y), c*(O1.y-O1.x));   // w8^1 * O1
    cplx u2=C2(O2.y, -O2.x);                    // -i * O2
    cplx v3=C2(c*(O3.y-O3.x), -c*(O3.x+O3.y));  // w8^3 * O3
    float4 w12 = tw12[toff + n];
    cplx w1 = C2(w12.x, w12.y), w2 = C2(w12.z, w12.w);
    float2 w3l = tw3t[toff + n];
    cplx w3 = C2(w3l.x, w3l.y);
    cplx w4 = cmul(w2,w2), w5 = cmul(w2,w3), w6 = cmul(w3,w3), w7 = cmul(w3,w4);
    d[0] = E0+O0;
    d[1] = cmul(E1+t1, w1);
    d[2] = cmul(E2+u2, w2);
    d[3] = cmul(E3+v3, w3);
    d[4] = cmul(E0-O0, w4);
    d[5] = cmul(E1-t1, w5);
    d[6] = cmul(E2-u2, w6);
    d[7] = cmul(E3-v3, w7);
}

// ---------------- radix-8 inverse core: conj-twiddle then inverse butterfly ----------------
__device__ __forceinline__ void r8i(cplx* d, const float4* __restrict__ tw12,
                                    const float2* __restrict__ tw3t, int n, int toff){
    float4 w12 = tw12[toff + n];
    cplx w1 = C2(w12.x, w12.y), w2 = C2(w12.z, w12.w);
    float2 w3l = tw3t[toff + n];
    cplx w3 = C2(w3l.x, w3l.y);
    cplx w4 = cmul(w2,w2), w5 = cmul(w2,w3), w6 = cmul(w3,w3), w7 = cmul(w3,w4);
    d[1]=cmulc(d[1],w1); d[2]=cmulc(d[2],w2); d[3]=cmulc(d[3],w3); d[4]=cmulc(d[4],w4);
    d[5]=cmulc(d[5],w5); d[6]=cmulc(d[6],w6); d[7]=cmulc(d[7],w7);
    cplx EA0=d[0]+d[4], EA1=d[0]-d[4];
    cplx EB0=d[2]+d[6], EB1=d[2]-d[6];
    cplx OA0=d[1]+d[5], OA1=d[1]-d[5];
    cplx OB0=d[3]+d[7], OB1=d[3]-d[7];
    cplx E0=EA0+EB0, E2=EA0-EB0;
    cplx E1=C2(EA1.x-EB1.y, EA1.y+EB1.x);   // EA1 + i*EB1
    cplx E3=C2(EA1.x+EB1.y, EA1.y-EB1.x);
    cplx O0=OA0+OB0, O2=OA0-OB0;
    cplx O1=C2(OA1.x-OB1.y, OA1.y+OB1.x);
    cplx O3=C2(OA1.x+OB1.y, OA1.y-OB1.x);
    const float c = RSQRT2;
    cplx t1=C2(c*(O1.x-O1.y), c*(O1.y+O1.x));    // conj(w8)*O1
    cplx u2=C2(-O2.y, O2.x);                     // +i*O2
    cplx v3=C2(-c*(O3.x+O3.y), c*(O3.x-O3.y));   // conj(w8^3)*O3
    d[0] = E0+O0;
    d[1] = E1+t1;
    d[2] = E2+u2;
    d[3] = E3+v3;
    d[4] = E0-O0;
    d[5] = E1-t1;
    d[6] = E2-u2;
    d[7] = E3-v3;
}

// rounds B, C, D of forward FFT (round A done by caller in registers)
__device__ __forceinline__ void fft_fwd_rest(cplx* s, const float4* __restrict__ tw12,
                                             const float2* __restrict__ tw3t, int tid){
    __syncthreads();
    {   // round B, stride 32
        int base = (tid>>5)*256 + (tid&31);
        cplx d[8];
#pragma unroll
        for (int q = 0; q < 8; ++q) d[q] = s[SW(base + 32*q)];
        r8f(d, tw12, tw3t, tid&31, 256);
#pragma unroll
        for (int q = 0; q < 8; ++q) s[SW(base + 32*q)] = d[q];
    }
    __syncthreads();
    {   // round C, stride 4
        int base = (tid>>2)*32 + (tid&3);
        cplx d[8];
#pragma unroll
        for (int q = 0; q < 8; ++q) d[q] = s[SW(base + 4*q)];
        r8f(d, tw12, tw3t, tid&3, 288);
#pragma unroll
        for (int q = 0; q < 8; ++q) s[SW(base + 4*q)] = d[q];
    }
    __syncthreads();
    {   // round D: radix-4 span-1, trivial twiddle, contiguous 8/thread
        int g8 = 8*tid;
#pragma unroll
        for (int h = 0; h < 2; ++h) {
            int b4 = g8 + 4*h;
            cplx x0=s[SW(b4)], x1=s[SW(b4+1)], x2=s[SW(b4+2)], x3=s[SW(b4+3)];
            cplx A0=x0+x2, A1=x0-x2;
            cplx B0=x1+x3, B1=x1-x3;
            s[SW(b4)]   = A0+B0;
            s[SW(b4+1)] = C2(A1.x + B1.y, A1.y - B1.x);  // A1 - i*B1
            s[SW(b4+2)] = A0-B0;
            s[SW(b4+3)] = C2(A1.x - B1.y, A1.y + B1.x);  // A1 + i*B1
        }
    }
    __syncthreads();
}

// rounds D', C', B' of inverse FFT; caller does round A' in registers afterwards
__device__ __forceinline__ void fft_inv_rest(cplx* s, const float4* __restrict__ tw12,
                                             const float2* __restrict__ tw3t, int tid){
    {   // radix-4 span-1 inverse
        int g8 = 8*tid;
#pragma unroll
        for (int h = 0; h < 2; ++h) {
            int b4 = g8 + 4*h;
            cplx z0=s[SW(b4)], z1=s[SW(b4+1)], z2=s[SW(b4+2)], z3=s[SW(b4+3)];
            cplx A0=z0+z2, A1=z0-z2;
            cplx B0=z1+z3, B1=z1-z3;
            s[SW(b4)]   = A0+B0;
            s[SW(b4+1)] = C2(A1.x - B1.y, A1.y + B1.x);  // A1 + i*B1
            s[SW(b4+2)] = A0-B0;
            s[SW(b4+3)] = C2(A1.x + B1.y, A1.y - B1.x);  // A1 - i*B1
        }
    }
    __syncthreads();
    {   // C' stride 4
        int base = (tid>>2)*32 + (tid&3);
        cplx d[8];
#pragma unroll
        for (int q = 0; q < 8; ++q) d[q] = s[SW(base + 4*q)];
        r8i(d, tw12, tw3t, tid&3, 288);
#pragma unroll
        for (int q = 0; q < 8; ++q) s[SW(base + 4*q)] = d[q];
    }
    __syncthreads();
    {   // B' stride 32
        int base = (tid>>5)*256 + (tid&31);
        cplx d[8];
#pragma unroll
        for (int q = 0; q < 8; ++q) d[q] = s[SW(base + 32*q)];
        r8i(d, tw12, tw3t, tid&31, 256);
#pragma unroll
        for (int q = 0; q < 8; ++q) s[SW(base + 32*q)] = d[q];
    }
    __syncthreads();
}

// q = {th, ks, 1/kw, slope}; input is |X|^2
__device__ __forceinline__ float gr_of2(float a2, float4 q){
    float mag_db = 0.5f * DB_LOG2 * log2f(fmaxf(a2, 1e-16f));
    float over = mag_db - q.x;
    float hard = (mag_db < q.x) ? 0.0f : over*q.w;
    float kf = fminf(fmaxf((mag_db - q.y)*q.z, 0.0f), 1.0f);
    float kneeg = kf*kf*over*q.w;
    float ke = 2.0f*q.x - q.y;
    return (mag_db >= q.y && mag_db <= ke) ? kneeg : hard;
}

__device__ __forceinline__ cplx scale_bin(cplx X, float g){
    float a2 = X.x*X.x + X.y*X.y;
    if (a2 >= 1e-16f) return C2(g,g)*X;
    if (a2 > 0.f)  { float sc = g*1e-8f*rsqrtf(a2); return C2(sc,sc)*X; }
    return C2(g*1e-8f, 0.f);
}

// ---------------- init: twiddles + pair table {W, p, p2} + params + makeup pairs ----------------
__global__ __launch_bounds__(NT) void k_init(
    const float* __restrict__ thr, const float* __restrict__ ratio,
    const float* __restrict__ knee, const float* __restrict__ makeup,
    float4* __restrict__ tw12, float2* __restrict__ tw3t,
    float4* __restrict__ wp, float4* __restrict__ pa, float4* __restrict__ pb,
    float2* __restrict__ mkq2)
{
    int i = blockIdx.x*NT + threadIdx.x;
    if (i < TWN) {
        int n, len;
        if (i < 256)      { n = i;       len = 2048; }
        else if (i < 288) { n = i - 256; len = 256;  }
        else              { n = i - 288; len = 32;   }
        double ang = -2.0*PI_D*(double)n/(double)len;
        tw12[i] = make_float4((float)cos(ang), (float)sin(ang),
                              (float)cos(2.0*ang), (float)sin(2.0*ang));
        tw3t[i] = make_float2((float)cos(3.0*ang), (float)sin(3.0*ang));
    } else if (i < TWN + 1024) {
        int m = i - TWN;
        int p  = p_of_m(m);
        int k  = revm(p);
        int k2 = (k == 0) ? 2048 : 2048 - k;
        int p2 = pmap((2048 - k) & 2047);
        double ang = -PI_D*(double)k/2048.0;   // E(k/4096)
        wp[m] = make_float4((float)cos(ang), (float)sin(ang),
                            __int_as_float(p), __int_as_float(p2));
        float th = thr[k], ra = ratio[k], kw = knee[k];
        pa[m] = make_float4(th, th - 0.5f*kw, 1.0f/kw, 1.0f - 1.0f/ra);
        th = thr[k2]; ra = ratio[k2]; kw = knee[k2];
        pb[m] = make_float4(th, th - 0.5f*kw, 1.0f/kw, 1.0f - 1.0f/ra);
        mkq2[m] = make_float2(exp2f(makeup[k]  * DB2LIN_LOG2),
                              exp2f(makeup[k2] * DB2LIN_LOG2));
    } else if (i == TWN + 1024) {
        mkq2[1024] = make_float2(exp2f(makeup[1024] * DB2LIN_LOG2), 1.0f);
    }
}

// ---------------- kernel 1: STFT (round A fused with load); fp16 spec pairs + packed gr ----------------
template<int STORESPEC>
__global__ __launch_bounds__(NT, 8) void k_fwd(
    const float* __restrict__ audio, const float* __restrict__ window,
    const float* __restrict__ thr, const float* __restrict__ ratio,
    const float* __restrict__ knee,
    const float4* __restrict__ tw12, const float2* __restrict__ tw3t,
    const float4* __restrict__ wp, const float4* __restrict__ pa,
    const float4* __restrict__ pb,
    unsigned* __restrict__ gr, uint2* __restrict__ spec)
{
    __shared__ cplx s[SWSZ];
    const int tid = threadIdx.x;
    const int blk = blockIdx.x;
    const int bc  = blk / NFRAMES;
    const int f   = blk - bc*NFRAMES;

    const float2* a2c = (const float2*)(audio + (size_t)bc*NSAMP + (size_t)f*NHOP);
    const float2* w2c = (const float2*)window;
    {   // fused load + round A (stride 256), registers only
        cplx d[8];
#pragma unroll
        for (int q = 0; q < 8; ++q) {
            int n = tid + 256*q;
            float2 u = a2c[n], w = w2c[n];
            d[q] = C2(u.x*w.x, u.y*w.y);     // z[n] = x[2n]w + i x[2n+1]w
        }
        r8f(d, tw12, tw3t, tid, 0);
#pragma unroll
        for (int q = 0; q < 8; ++q) s[SW(tid + 256*q)] = d[q];
    }
    fft_fwd_rest(s, tw12, tw3t, tid);

    unsigned* grow = gr + (size_t)(bc*NFR2 + f) * RSTR;
    uint2* spx = spec + (size_t)(bc*NFRAMES + f) * SPSTR;
#pragma unroll
    for (int j = 0; j < 4; ++j) {
        int m  = tid + NT*j;
        float4 wpv = wp[m];
        int p  = __float_as_int(wpv.z);
        int p2 = __float_as_int(wpv.w);
        cplx Zk  = s[SW(p)];
        cplx Zk2 = s[SW(p2)];
        cplx Ze = C2(0.5f*(Zk.x + Zk2.x), 0.5f*(Zk.y - Zk2.y));
        cplx Zo = C2(0.5f*(Zk.y + Zk2.y), -0.5f*(Zk.x - Zk2.x));
        cplx W  = C2(wpv.x, wpv.y);
        cplx V  = cmul(W, Zo);
        cplx Xk  = Ze + V;                              // X[k]
        cplx Xk2 = C2(Ze.x - V.x, V.y - Ze.y);          // X[2048-k]
        if (STORESPEC)
            spx[m] = make_uint2(packh2(Xk.x, Xk.y), packh2(Xk2.x, Xk2.y));
        grow[m] = packh2(gr_of2(Xk.x*Xk.x + Xk.y*Xk.y,   pa[m]),
                         gr_of2(Xk2.x*Xk2.x + Xk2.y*Xk2.y, pb[m]));
    }
    if (tid == 0) {   // self-paired bin 1024 at slot pmap(1024)=2: X = conj(Z)
        cplx Z = s[SW(2)];
        if (STORESPEC) spx[1024] = make_uint2(packh2(Z.x, -Z.y), 0u);
        float th = thr[1024], ra = ratio[1024], kw = knee[1024];
        float4 q = make_float4(th, th - 0.5f*kw, 1.0f/kw, 1.0f - 1.0f/ra);
        grow[1024] = packh2(gr_of2(Z.x*Z.x + Z.y*Z.y, q), 0.f);
    }
}

// ---------------- kernel 2: attack/release scan; two env chains per thread, uint I/O ----------------
__global__ __launch_bounds__(STH) void k_smooth(
    unsigned* __restrict__ gr, const float2* __restrict__ mkq2)
{
    int gid = blockIdx.x*STH + threadIdx.x;
    if (gid >= NBC*RSTR) return;
    int bc = gid / RSTR;
    int m  = gid - bc*RSTR;
    float2 mk = mkq2[m];
    unsigned* p = gr + (size_t)bc*NFR2*RSTR + m;

    float env1 = 0.f, env2 = 0.f;
    unsigned curv[8], nxtv[8];
#pragma unroll
    for (int d = 0; d < 8; ++d) curv[d] = p[(size_t)d*RSTR];
    for (int c = 0; c < 512; c += 8) {
        if (c < 504) {
#pragma unroll
            for (int d = 0; d < 8; ++d) nxtv[d] = p[(size_t)(c+8+d)*RSTR];
        }
        float t1[8], t2[8];
#pragma unroll
        for (int d = 0; d < 8; ++d) {
            cplx gdb = unpackh2(curv[d]);
            t1[d] = exp2f(gdb.x * -DB2LIN_LOG2);     // tgt, indep of env
            t2[d] = exp2f(gdb.y * -DB2LIN_LOG2);
        }
#pragma unroll
        for (int d = 0; d < 8; ++d) {
            float c1 = (t1[d] < env1) ? A_COEFF : R_COEFF;
            env1 = fmaf(c1, t1[d] - env1, env1);
            float c2 = (t2[d] < env2) ? A_COEFF : R_COEFF;
            env2 = fmaf(c2, t2[d] - env2, env2);
            curv[d] = packh2(fmaxf(env1, 1e-8f) * mk.x,
                             fmaxf(env2, 1e-8f) * mk.y);
        }
#pragma unroll
        for (int d = 0; d < 8; ++d) p[(size_t)(c+d)*RSTR] = curv[d];
#pragma unroll
        for (int d = 0; d < 8; ++d) curv[d] = nxtv[d];
    }
}

// repack scaled pair (XSk, XSk2) of bin k into packed-spectrum LDS slots (p, p2)
__device__ __forceinline__ void repack_pair(cplx* s, cplx XSk, cplx XSk2,
                                            cplx W, int p, int p2){
    // Z'[k] = E + i*conj(W)*P ; Z'[k2] = conj(E) + i*W*conj(P)
    cplx E = C2(0.5f*(XSk.x + XSk2.x), 0.5f*(XSk.y - XSk2.y));
    cplx P = C2(0.5f*(XSk.x - XSk2.x), 0.5f*(XSk.y + XSk2.y));
    cplx Wc = C2(W.x, -W.y);
    cplx Q  = cmul(Wc, P);
    cplx Pc = C2(P.x, -P.y);
    cplx R  = cmul(W, Pc);
    s[SW(p)]  = C2(E.x - Q.y, E.y + Q.x);
    s[SW(p2)] = C2(E.x - R.y, R.x - E.y);
}

// MODE 1: spec -> scale -> ifft -> ca fp16 (in place over spec row)
// MODE 2: fallback — recompute fwd FFT from audio, scale, ifft, RMW out (4 passes)
template<int MODE>
__global__ __launch_bounds__(NT, 8) void k_inv(
    const float* __restrict__ audio, const float* __restrict__ window,
    const unsigned* __restrict__ gains,
    const float4* __restrict__ tw12, const float2* __restrict__ tw3t,
    const float4* __restrict__ wp,
    uint2* __restrict__ spec, float* __restrict__ out, int pass, int nfp)
{
    __shared__ cplx s[SWSZ];
    const int tid = threadIdx.x;
    const int blk = blockIdx.x;
    int bc, f;
    if (MODE != 2) { bc = blk / NFRAMES; f = blk - bc*NFRAMES; }
    else           { bc = blk / nfp;     f = pass + 4*(blk - bc*nfp); }

    const float2* w2c = (const float2*)window;
    const unsigned* grow = gains + (size_t)(bc*NFR2 + f) * RSTR;
    uint2* spx = spec + (size_t)(bc*NFRAMES + f) * SPSTR;

    if (MODE != 2) {
        // scale + repack directly from fp16 spec pairs (no FFT, no unpack)
#pragma unroll
        for (int j = 0; j < 4; ++j) {
            int m = tid + NT*j;
            uint2 v = spx[m];
            float4 wpv = wp[m];
            cplx gg = unpackh2(grow[m]);
            cplx XSk  = scale_bin(unpackh2(v.x), gg.x);
            cplx XSk2 = scale_bin(unpackh2(v.y), gg.y);
            repack_pair(s, XSk, XSk2, C2(wpv.x, wpv.y),
                        __float_as_int(wpv.z), __float_as_int(wpv.w));
        }
        if (tid == 0) {
            uint2 v = spx[1024];
            cplx gg = unpackh2(grow[1024]);
            cplx XS = scale_bin(unpackh2(v.x), gg.x);
            s[SW(2)] = C2(XS.x, -XS.y);     // Z' = conj(XS)
        }
        __syncthreads();
    } else {
        {   // fused load + forward round A
            const float2* a2c = (const float2*)(audio + (size_t)bc*NSAMP + (size_t)f*NHOP);
            cplx d[8];
#pragma unroll
            for (int q = 0; q < 8; ++q) {
                int n = tid + 256*q;
                float2 u = a2c[n], w = w2c[n];
                d[q] = C2(u.x*w.x, u.y*w.y);
            }
            r8f(d, tw12, tw3t, tid, 0);
#pragma unroll
            for (int q = 0; q < 8; ++q) s[SW(tid + 256*q)] = d[q];
        }
        fft_fwd_rest(s, tw12, tw3t, tid);
        // unpack + scale + repack in place
#pragma unroll
        for (int j = 0; j < 4; ++j) {
            int m = tid + NT*j;
            float4 wpv = wp[m];
            int p  = __float_as_int(wpv.z);
            int p2 = __float_as_int(wpv.w);
            cplx Zk  = s[SW(p)];
            cplx Zk2 = s[SW(p2)];
            cplx Ze = C2(0.5f*(Zk.x + Zk2.x), 0.5f*(Zk.y - Zk2.y));
            cplx Zo = C2(0.5f*(Zk.y + Zk2.y), -0.5f*(Zk.x - Zk2.x));
            cplx W  = C2(wpv.x, wpv.y);
            cplx V  = cmul(W, Zo);
            cplx Xk  = Ze + V;
            cplx Xk2 = C2(Ze.x - V.x, V.y - Ze.y);
            cplx gg = unpackh2(grow[m]);
            cplx XSk  = scale_bin(Xk,  gg.x);
            cplx XSk2 = scale_bin(Xk2, gg.y);
            repack_pair(s, XSk, XSk2, W, p, p2);
        }
        if (tid == 0) {
            cplx Z  = s[SW(2)];
            cplx gg = unpackh2(grow[1024]);
            cplx XS = scale_bin(C2(Z.x, -Z.y), gg.x);
            s[SW(2)] = C2(XS.x, -XS.y);
        }
        __syncthreads();
    }

    fft_inv_rest(s, tw12, tw3t, tid);

    const float invn = 1.0f/2048.0f;
    {   // round A' (stride 256) in registers -> global write
        cplx d[8];
#pragma unroll
        for (int q = 0; q < 8; ++q) d[q] = s[SW(tid + 256*q)];
        r8i(d, tw12, tw3t, tid, 0);
        if (MODE == 1) {
            unsigned* caH = (unsigned*)spx;      // overwrite spec row with fp16 ca
#pragma unroll
            for (int q = 0; q < 8; ++q) {
                int n = tid + 256*q;
                float2 w = w2c[n];
                caH[n] = packh2(d[q].x*w.x*invn, d[q].y*w.y*invn);
            }
        } else {
            float2* dst2 = (float2*)(out + (size_t)bc*NSAMP + (size_t)f*NHOP);
#pragma unroll
            for (int q = 0; q < 8; ++q) {
                int n = tid + 256*q;
                float2 w = w2c[n];
                float2 o = dst2[n];
                o.x += d[q].x * w.x * invn;
                o.y += d[q].y * w.y * invn;
                dst2[n] = o;
            }
        }
    }
}

// ---------------- kernel 4: overlap-add gather over fp16 ca rows (in spec buffer) ----------------
__global__ __launch_bounds__(NT) void k_ola(
    const uint2* __restrict__ spec, float* __restrict__ out)
{
    const int blk = blockIdx.x;
    const int bc = blk >> 9;          // 512 tiles of 1024 samples
    const int ti = blk & 511;
    const int tid = threadIdx.x;
    float4 acc = make_float4(0.f, 0.f, 0.f, 0.f);
    int flo = ti - 3; if (flo < 0) flo = 0;
    int fhi = ti; if (fhi > NFRAMES - 1) fhi = NFRAMES - 1;
    for (int f = flo; f <= fhi; ++f) {
        const uint2* row = spec + (size_t)(bc*NFRAMES + f) * SPSTR;
        uint2 v = row[(ti - f)*256 + tid];
        cplx a = unpackh2(v.x), b = unpackh2(v.y);
        acc.x += a.x; acc.y += a.y; acc.z += b.x; acc.w += b.y;
    }
    ((float4*)(out + (size_t)bc*NSAMP))[ti*256 + tid] = acc;
}

extern "C" void kernel_launch(void* const* d_in, const int* in_sizes, int n_in,
                              void* d_out, int out_size, void* d_ws, size_t ws_size,
                              hipStream_t stream)
{
    const float* audio  = (const float*)d_in[0];
    const float* window = (const float*)d_in[1];
    const float* thr    = (const float*)d_in[2];
    const float* ratio  = (const float*)d_in[3];
    const float* makeup = (const float*)d_in[4];
    const float* knee   = (const float*)d_in[5];
    float* out = (float*)d_out;

    char* base = (char*)d_ws;
    float4* tw12 = (float4*)base;
    float2* tw3t = (float2*)(base + 8192);
    float4* wp   = (float4*)(base + 16384);
    float4* pa   = (float4*)(base + 32768);
    float4* pb   = (float4*)(base + 49152);
    float2* mkq2 = (float2*)(base + 65536);
    unsigned* gr = (unsigned*)(base + WSHDR);
    const size_t grB = (size_t)NBC*NFR2*RSTR*sizeof(unsigned);           // 34.1 MB
    const size_t spB = (size_t)NBC*NFRAMES*SPSTR*sizeof(uint2);          // 66.8 MB
    const size_t needB = WSHDR + grB + spB;          // fp16 ca reuses spec buffer

    dim3 blkd(NT);
    k_init<<<dim3((TWN + 1025 + NT - 1)/NT), blkd, 0, stream>>>(
        thr, ratio, knee, makeup, tw12, tw3t, wp, pa, pb, mkq2);

    int sblocks = (NBC*RSTR + STH - 1)/STH;
    if (ws_size >= needB) {
        uint2* spec = (uint2*)(base + WSHDR + grB);
        k_fwd<1><<<dim3(NBC*NFRAMES), blkd, 0, stream>>>(
            audio, window, thr, ratio, knee, tw12, tw3t, wp, pa, pb, gr, spec);
        k_smooth<<<dim3(sblocks), dim3(STH), 0, stream>>>(gr, mkq2);
        k_inv<1><<<dim3(NBC*NFRAMES), blkd, 0, stream>>>(
            audio, window, gr, tw12, tw3t, wp, spec, out, 0, 0);
        k_ola<<<dim3(NBC*512), blkd, 0, stream>>>(spec, out);
    } else {
        hipMemsetAsync(d_out, 0, (size_t)out_size*sizeof(float), stream);
        uint2* spec = (uint2*)(base + WSHDR + grB);   // unused in MODE 2
        k_fwd<0><<<dim3(NBC*NFRAMES), blkd, 0, stream>>>(
            audio, window, thr, ratio, knee, tw12, tw3t, wp, pa, pb, gr, spec);
        k_smooth<<<dim3(sblocks), dim3(STH), 0, stream>>>(gr, mkq2);
        for (int pass = 0; pass < 4; ++pass) {
            int nfp = (NFRAMES - pass + 3) / 4;
            k_inv<2><<<dim3(NBC*nfp), blkd, 0, stream>>>(
                audio, window, gr, tw12, tw3t, wp, spec, out, pass, nfp);
        }
    }
}

// Round 12
// 168.612 us; speedup vs baseline: 1.8986x; 1.0926x over previous
//
#include <hip/hip_runtime.h>
#include <hip/hip_fp16.h>

#define NFFT     4096
#define NC       2048      // complex FFT length (real-packed)
#define NHOP     1024
#define NK       2049
#define NBC      16
#define NSAMP    524288
#define NFRAMES  509
#define NFR2     520       // padded frame rows for branch-free smooth prefetch
#define NT       256
#define STH      64        // k_smooth block size
#define SPSTR    1025      // spec row stride in uint2 (1024 pairs + bin1024)
#define RSTR     1025      // gr row stride in uint (1024 pairs + bin1024)

#define A_COEFF 0.0022650046943f     // 1 - exp(-1/441)
#define R_COEFF 0.00022673165872f    // 1 - exp(-1/4410)
#define DB2LIN_LOG2 0.16609640474436812f  // log2(10)/20
#define DB_LOG2     6.02059991327962390f  // 20*log10(2)
#define PI_D 3.14159265358979323846264338327950288

// LDS swizzle: ~2-way max at every FFT stage
#define SW(e) ((e) + 7*((e)>>5))
#define SWSZ 2489      // SW(2047)+1  -> 19912 B LDS = 8 blocks/CU
#define TWN  292       // radix-8 stage tables: 256(A) + 32(B) + 4(C)
// ws header (bytes): tw12@0, tw3t@8192, wp@16384, pa@32768, pb@49152, mkq2@65536
#define WSHDR 131072

// packed-f32 complex: lane0=re, lane1=im -> v_pk_* dual-issue on gfx950
typedef float cplx __attribute__((ext_vector_type(2)));
#define C2(a,b) ((cplx){(float)(a), (float)(b)})

__device__ __forceinline__ cplx cmul(cplx a, cplx b){
    cplx p = C2(a.x, a.x) * b;                 // (ax*br, ax*bi)
    cplx q = C2(a.y, a.y) * C2(b.y, b.x);      // (ay*bi, ay*br)
    return C2(p.x - q.x, p.y + q.y);           // pk_add with neg_lo
}
__device__ __forceinline__ cplx cmulc(cplx a, cplx b){   // a * conj(b)
    cplx p = C2(a.x, a.x) * b;
    cplx q = C2(a.y, a.y) * C2(b.y, b.x);
    return C2(p.x + q.x, q.y - p.y);
}

union HU { unsigned u; __half2 h; };
__device__ __forceinline__ unsigned packh2(float a, float b){
    HU x; x.h = __floats2half2_rn(a, b); return x.u;
}
__device__ __forceinline__ cplx unpackh2(unsigned v){
    HU x; x.u = v; float2 r = __half22float2(x.h); return C2(r.x, r.y);
}

#define RSQRT2 0.70710678118654752f

// mixed-radix (8,8,8,4) digit scramble (host-side tables only)
__device__ __forceinline__ int revm(int p){
    return (p>>8) + 8*((p>>5)&7) + 64*((p>>2)&7) + 512*(p&3);
}
__device__ __forceinline__ int pmap(int k){
    return ((k&7)<<8) | (((k>>3)&7)<<5) | (((k>>6)&7)<<2) | ((k>>9)&3);
}
__device__ __forceinline__ int p_of_m(int m){ return ((m>>1)<<2) | (m&1); }

// ---------------- radix-8 forward core: butterfly then twiddle, in place ----------------
__device__ __forceinline__ void r8f(cplx* d, const float4* __restrict__ tw12,
                                    const float2* __restrict__ tw3t, int n, int toff){
    cplx EA0=d[0]+d[4], EA1=d[0]-d[4];
    cplx EB0=d[2]+d[6], EB1=d[2]-d[6];
    cplx OA0=d[1]+d[5], OA1=d[1]-d[5];
    cplx OB0=d[3]+d[7], OB1=d[3]-d[7];
    cplx E0=EA0+EB0, E2=EA0-EB0;
    cplx E1=C2(EA1.x+EB1.y, EA1.y-EB1.x);   // EA1 - i*EB1
    cplx E3=C2(EA1.x-EB1.y, EA1.y+EB1.x);   // EA1 + i*EB1
    cplx O0=OA0+OB0, O2=OA0-OB0;
    cplx O1=C2(OA1.x+OB1.y, OA1.y-OB1.x);
    cplx O3=C2(OA1.x-OB1.y, OA1.y+OB1.x);
    const float c = RSQRT2;
    cplx t1=C2(c*(O1.x+O1.y), c*(O1.y-O1.x));   // w8^1 * O1
    cplx u2=C2(O2.y, -O2.x);                    // -i * O2
    cplx v3=C2(c*(O3.y-O3.x), -c*(O3.x+O3.y));  // w8^3 * O3
    float4 w12 = tw12[toff + n];
    cplx w1 = C2(w12.x, w12.y), w2 = C2(w12.z, w12.w);
    float2 w3l = tw3t[toff + n];
    cplx w3 = C2(w3l.x, w3l.y);
    cplx w4 = cmul(w2,w2), w5 = cmul(w2,w3), w6 = cmul(w3,w3), w7 = cmul(w3,w4);
    d[0] = E0+O0;
    d[1] = cmul(E1+t1, w1);
    d[2] = cmul(E2+u2, w2);
    d[3] = cmul(E3+v3, w3);
    d[4] = cmul(E0-O0, w4);
    d[5] = cmul(E1-t1, w5);
    d[6] = cmul(E2-u2, w6);
    d[7] = cmul(E3-v3, w7);
}

// ---------------- radix-8 inverse core: conj-twiddle then inverse butterfly ----------------
__device__ __forceinline__ void r8i(cplx* d, const float4* __restrict__ tw12,
                                    const float2* __restrict__ tw3t, int n, int toff){
    float4 w12 = tw12[toff + n];
    cplx w1 = C2(w12.x, w12.y), w2 = C2(w12.z, w12.w);
    float2 w3l = tw3t[toff + n];
    cplx w3 = C2(w3l.x, w3l.y);
    cplx w4 = cmul(w2,w2), w5 = cmul(w2,w3), w6 = cmul(w3,w3), w7 = cmul(w3,w4);
    d[1]=cmulc(d[1],w1); d[2]=cmulc(d[2],w2); d[3]=cmulc(d[3],w3); d[4]=cmulc(d[4],w4);
    d[5]=cmulc(d[5],w5); d[6]=cmulc(d[6],w6); d[7]=cmulc(d[7],w7);
    cplx EA0=d[0]+d[4], EA1=d[0]-d[4];
    cplx EB0=d[2]+d[6], EB1=d[2]-d[6];
    cplx OA0=d[1]+d[5], OA1=d[1]-d[5];
    cplx OB0=d[3]+d[7], OB1=d[3]-d[7];
    cplx E0=EA0+EB0, E2=EA0-EB0;
    cplx E1=C2(EA1.x-EB1.y, EA1.y+EB1.x);   // EA1 + i*EB1
    cplx E3=C2(EA1.x+EB1.y, EA1.y-EB1.x);
    cplx O0=OA0+OB0, O2=OA0-OB0;
    cplx O1=C2(OA1.x-OB1.y, OA1.y+OB1.x);
    cplx O3=C2(OA1.x+OB1.y, OA1.y-OB1.x);
    const float c = RSQRT2;
    cplx t1=C2(c*(O1.x-O1.y), c*(O1.y+O1.x));    // conj(w8)*O1
    cplx u2=C2(-O2.y, O2.x);                     // +i*O2
    cplx v3=C2(-c*(O3.x+O3.y), c*(O3.x-O3.y));   // conj(w8^3)*O3
    d[0] = E0+O0;
    d[1] = E1+t1;
    d[2] = E2+u2;
    d[3] = E3+v3;
    d[4] = E0-O0;
    d[5] = E1-t1;
    d[6] = E2-u2;
    d[7] = E3-v3;
}

// rounds B, C, D of forward FFT (round A done by caller in registers)
__device__ __forceinline__ void fft_fwd_rest(cplx* s, const float4* __restrict__ tw12,
                                             const float2* __restrict__ tw3t, int tid){
    __syncthreads();
    {   // round B, stride 32
        int base = (tid>>5)*256 + (tid&31);
        cplx d[8];
#pragma unroll
        for (int q = 0; q < 8; ++q) d[q] = s[SW(base + 32*q)];
        r8f(d, tw12, tw3t, tid&31, 256);
#pragma unroll
        for (int q = 0; q < 8; ++q) s[SW(base + 32*q)] = d[q];
    }
    __syncthreads();
    {   // round C, stride 4
        int base = (tid>>2)*32 + (tid&3);
        cplx d[8];
#pragma unroll
        for (int q = 0; q < 8; ++q) d[q] = s[SW(base + 4*q)];
        r8f(d, tw12, tw3t, tid&3, 288);
#pragma unroll
        for (int q = 0; q < 8; ++q) s[SW(base + 4*q)] = d[q];
    }
    __syncthreads();
    {   // round D: radix-4 span-1, trivial twiddle, contiguous 8/thread
        int g8 = 8*tid;
#pragma unroll
        for (int h = 0; h < 2; ++h) {
            int b4 = g8 + 4*h;
            cplx x0=s[SW(b4)], x1=s[SW(b4+1)], x2=s[SW(b4+2)], x3=s[SW(b4+3)];
            cplx A0=x0+x2, A1=x0-x2;
            cplx B0=x1+x3, B1=x1-x3;
            s[SW(b4)]   = A0+B0;
            s[SW(b4+1)] = C2(A1.x + B1.y, A1.y - B1.x);  // A1 - i*B1
            s[SW(b4+2)] = A0-B0;
            s[SW(b4+3)] = C2(A1.x - B1.y, A1.y + B1.x);  // A1 + i*B1
        }
    }
    __syncthreads();
}

// rounds D', C', B' of inverse FFT; caller does round A' in registers afterwards
__device__ __forceinline__ void fft_inv_rest(cplx* s, const float4* __restrict__ tw12,
                                             const float2* __restrict__ tw3t, int tid){
    {   // radix-4 span-1 inverse
        int g8 = 8*tid;
#pragma unroll
        for (int h = 0; h < 2; ++h) {
            int b4 = g8 + 4*h;
            cplx z0=s[SW(b4)], z1=s[SW(b4+1)], z2=s[SW(b4+2)], z3=s[SW(b4+3)];
            cplx A0=z0+z2, A1=z0-z2;
            cplx B0=z1+z3, B1=z1-z3;
            s[SW(b4)]   = A0+B0;
            s[SW(b4+1)] = C2(A1.x - B1.y, A1.y + B1.x);  // A1 + i*B1
            s[SW(b4+2)] = A0-B0;
            s[SW(b4+3)] = C2(A1.x + B1.y, A1.y - B1.x);  // A1 - i*B1
        }
    }
    __syncthreads();
    {   // C' stride 4
        int base = (tid>>2)*32 + (tid&3);
        cplx d[8];
#pragma unroll
        for (int q = 0; q < 8; ++q) d[q] = s[SW(base + 4*q)];
        r8i(d, tw12, tw3t, tid&3, 288);
#pragma unroll
        for (int q = 0; q < 8; ++q) s[SW(base + 4*q)] = d[q];
    }
    __syncthreads();
    {   // B' stride 32
        int base = (tid>>5)*256 + (tid&31);
        cplx d[8];
#pragma unroll
        for (int q = 0; q < 8; ++q) d[q] = s[SW(base + 32*q)];
        r8i(d, tw12, tw3t, tid&31, 256);
#pragma unroll
        for (int q = 0; q < 8; ++q) s[SW(base + 32*q)] = d[q];
    }
    __syncthreads();
}

// q = {th, ks, 1/kw, slope}; input is |X|^2
__device__ __forceinline__ float gr_of2(float a2, float4 q){
    float mag_db = 0.5f * DB_LOG2 * log2f(fmaxf(a2, 1e-16f));
    float over = mag_db - q.x;
    float hard = (mag_db < q.x) ? 0.0f : over*q.w;
    float kf = fminf(fmaxf((mag_db - q.y)*q.z, 0.0f), 1.0f);
    float kneeg = kf*kf*over*q.w;
    float ke = 2.0f*q.x - q.y;
    return (mag_db >= q.y && mag_db <= ke) ? kneeg : hard;
}

__device__ __forceinline__ cplx scale_bin(cplx X, float g){
    float a2 = X.x*X.x + X.y*X.y;
    if (a2 >= 1e-16f) return C2(g,g)*X;
    if (a2 > 0.f)  { float sc = g*1e-8f*rsqrtf(a2); return C2(sc,sc)*X; }
    return C2(g*1e-8f, 0.f);
}

// ---------------- init: twiddles + pair table {W, p, p2} + params + makeup pairs ----------------
__global__ __launch_bounds__(NT) void k_init(
    const float* __restrict__ thr, const float* __restrict__ ratio,
    const float* __restrict__ knee, const float* __restrict__ makeup,
    float4* __restrict__ tw12, float2* __restrict__ tw3t,
    float4* __restrict__ wp, float4* __restrict__ pa, float4* __restrict__ pb,
    float2* __restrict__ mkq2)
{
    int i = blockIdx.x*NT + threadIdx.x;
    if (i < TWN) {
        int n, len;
        if (i < 256)      { n = i;       len = 2048; }
        else if (i < 288) { n = i - 256; len = 256;  }
        else              { n = i - 288; len = 32;   }
        double ang = -2.0*PI_D*(double)n/(double)len;
        tw12[i] = make_float4((float)cos(ang), (float)sin(ang),
                              (float)cos(2.0*ang), (float)sin(2.0*ang));
        tw3t[i] = make_float2((float)cos(3.0*ang), (float)sin(3.0*ang));
    } else if (i < TWN + 1024) {
        int m = i - TWN;
        int p  = p_of_m(m);
        int k  = revm(p);
        int k2 = (k == 0) ? 2048 : 2048 - k;
        int p2 = pmap((2048 - k) & 2047);
        double ang = -PI_D*(double)k/2048.0;   // E(k/4096)
        wp[m] = make_float4((float)cos(ang), (float)sin(ang),
                            __int_as_float(p), __int_as_float(p2));
        float th = thr[k], ra = ratio[k], kw = knee[k];
        pa[m] = make_float4(th, th - 0.5f*kw, 1.0f/kw, 1.0f - 1.0f/ra);
        th = thr[k2]; ra = ratio[k2]; kw = knee[k2];
        pb[m] = make_float4(th, th - 0.5f*kw, 1.0f/kw, 1.0f - 1.0f/ra);
        mkq2[m] = make_float2(exp2f(makeup[k]  * DB2LIN_LOG2),
                              exp2f(makeup[k2] * DB2LIN_LOG2));
    } else if (i == TWN + 1024) {
        mkq2[1024] = make_float2(exp2f(makeup[1024] * DB2LIN_LOG2), 1.0f);
    }
}

// ---------------- kernel 1: STFT (round A fused with load); fp16 spec pairs + packed gr ----------------
template<int STORESPEC>
__global__ __launch_bounds__(NT, 8) void k_fwd(
    const float* __restrict__ audio, const float* __restrict__ window,
    const float* __restrict__ thr, const float* __restrict__ ratio,
    const float* __restrict__ knee,
    const float4* __restrict__ tw12, const float2* __restrict__ tw3t,
    const float4* __restrict__ wp, const float4* __restrict__ pa,
    const float4* __restrict__ pb,
    unsigned* __restrict__ gr, uint2* __restrict__ spec)
{
    __shared__ cplx s[SWSZ];
    const int tid = threadIdx.x;
    const int blk = blockIdx.x;
    const int bc  = blk / NFRAMES;
    const int f   = blk - bc*NFRAMES;

    const float2* a2c = (const float2*)(audio + (size_t)bc*NSAMP + (size_t)f*NHOP);
    const float2* w2c = (const float2*)window;
    {   // fused load + round A (stride 256), registers only
        cplx d[8];
#pragma unroll
        for (int q = 0; q < 8; ++q) {
            int n = tid + 256*q;
            float2 u = a2c[n], w = w2c[n];
            d[q] = C2(u.x*w.x, u.y*w.y);     // z[n] = x[2n]w + i x[2n+1]w
        }
        r8f(d, tw12, tw3t, tid, 0);
#pragma unroll
        for (int q = 0; q < 8; ++q) s[SW(tid + 256*q)] = d[q];
    }
    fft_fwd_rest(s, tw12, tw3t, tid);

    unsigned* grow = gr + (size_t)(bc*NFR2 + f) * RSTR;
    uint2* spx = spec + (size_t)(bc*NFRAMES + f) * SPSTR;
#pragma unroll
    for (int j = 0; j < 4; ++j) {
        int m  = tid + NT*j;
        float4 wpv = wp[m];
        int p  = __float_as_int(wpv.z);
        int p2 = __float_as_int(wpv.w);
        cplx Zk  = s[SW(p)];
        cplx Zk2 = s[SW(p2)];
        cplx Ze = C2(0.5f*(Zk.x + Zk2.x), 0.5f*(Zk.y - Zk2.y));
        cplx Zo = C2(0.5f*(Zk.y + Zk2.y), -0.5f*(Zk.x - Zk2.x));
        cplx W  = C2(wpv.x, wpv.y);
        cplx V  = cmul(W, Zo);
        cplx Xk  = Ze + V;                              // X[k]
        cplx Xk2 = C2(Ze.x - V.x, V.y - Ze.y);          // X[2048-k]
        if (STORESPEC)
            spx[m] = make_uint2(packh2(Xk.x, Xk.y), packh2(Xk2.x, Xk2.y));
        grow[m] = packh2(gr_of2(Xk.x*Xk.x + Xk.y*Xk.y,   pa[m]),
                         gr_of2(Xk2.x*Xk2.x + Xk2.y*Xk2.y, pb[m]));
    }
    if (tid == 0) {   // self-paired bin 1024 at slot pmap(1024)=2: X = conj(Z)
        cplx Z = s[SW(2)];
        if (STORESPEC) spx[1024] = make_uint2(packh2(Z.x, -Z.y), 0u);
        float th = thr[1024], ra = ratio[1024], kw = knee[1024];
        float4 q = make_float4(th, th - 0.5f*kw, 1.0f/kw, 1.0f - 1.0f/ra);
        grow[1024] = packh2(gr_of2(Z.x*Z.x + Z.y*Z.y, q), 0.f);
    }
}

// ---------------- kernel 2: attack/release scan; 32-frame SW pipeline, 32-frame prefetch ----------------
__device__ __forceinline__ void sm_batch8(unsigned* v, float& env1, float& env2,
                                          float2 mk, unsigned* p, int c){
    float t1[8], t2[8];
#pragma unroll
    for (int d = 0; d < 8; ++d) {
        cplx gdb = unpackh2(v[d]);
        t1[d] = exp2f(gdb.x * -DB2LIN_LOG2);     // tgt, indep of env
        t2[d] = exp2f(gdb.y * -DB2LIN_LOG2);
    }
#pragma unroll
    for (int d = 0; d < 8; ++d) {
        float c1 = (t1[d] < env1) ? A_COEFF : R_COEFF;
        env1 = fmaf(c1, t1[d] - env1, env1);
        float c2 = (t2[d] < env2) ? A_COEFF : R_COEFF;
        env2 = fmaf(c2, t2[d] - env2, env2);
        v[d] = packh2(fmaxf(env1, 1e-8f) * mk.x,
                      fmaxf(env2, 1e-8f) * mk.y);    // linear gain (log/exp cancels)
    }
#pragma unroll
    for (int d = 0; d < 8; ++d) p[(size_t)(c+d)*RSTR] = v[d];
}

__global__ __launch_bounds__(STH) void k_smooth(
    unsigned* __restrict__ gr, const float2* __restrict__ mkq2)
{
    int gid = blockIdx.x*STH + threadIdx.x;
    if (gid >= NBC*RSTR) return;
    int bc = gid / RSTR;
    int m  = gid - bc*RSTR;
    float2 mk = mkq2[m];
    unsigned* p = gr + (size_t)bc*NFR2*RSTR + m;

    float env1 = 0.f, env2 = 0.f;
    unsigned b[4][8], n[4][8];
#pragma unroll
    for (int g = 0; g < 4; ++g)
#pragma unroll
        for (int d = 0; d < 8; ++d) b[g][d] = p[(size_t)(8*g + d)*RSTR];

    for (int c = 0; c < 512; c += 32) {
        if (c < 480) {   // prefetch next 32 frames (reads <= frame 511 < NFR2)
#pragma unroll
            for (int g = 0; g < 4; ++g)
#pragma unroll
                for (int d = 0; d < 8; ++d)
                    n[g][d] = p[(size_t)(c + 32 + 8*g + d)*RSTR];
        }
#pragma unroll
        for (int g = 0; g < 4; ++g)
            sm_batch8(b[g], env1, env2, mk, p, c + 8*g);
#pragma unroll
        for (int g = 0; g < 4; ++g)
#pragma unroll
            for (int d = 0; d < 8; ++d) b[g][d] = n[g][d];
    }
}

// repack scaled pair (XSk, XSk2) of bin k into packed-spectrum LDS slots (p, p2)
__device__ __forceinline__ void repack_pair(cplx* s, cplx XSk, cplx XSk2,
                                            cplx W, int p, int p2){
    // Z'[k] = E + i*conj(W)*P ; Z'[k2] = conj(E) + i*W*conj(P)
    cplx E = C2(0.5f*(XSk.x + XSk2.x), 0.5f*(XSk.y - XSk2.y));
    cplx P = C2(0.5f*(XSk.x - XSk2.x), 0.5f*(XSk.y + XSk2.y));
    cplx Wc = C2(W.x, -W.y);
    cplx Q  = cmul(Wc, P);
    cplx Pc = C2(P.x, -P.y);
    cplx R  = cmul(W, Pc);
    s[SW(p)]  = C2(E.x - Q.y, E.y + Q.x);
    s[SW(p2)] = C2(E.x - R.y, R.x - E.y);
}

// MODE 1: spec -> scale -> ifft -> ca fp16 (in place over spec row)
// MODE 2: fallback — recompute fwd FFT from audio, scale, ifft, RMW out (4 passes)
template<int MODE>
__global__ __launch_bounds__(NT, 8) void k_inv(
    const float* __restrict__ audio, const float* __restrict__ window,
    const unsigned* __restrict__ gains,
    const float4* __restrict__ tw12, const float2* __restrict__ tw3t,
    const float4* __restrict__ wp,
    uint2* __restrict__ spec, float* __restrict__ out, int pass, int nfp)
{
    __shared__ cplx s[SWSZ];
    const int tid = threadIdx.x;
    const int blk = blockIdx.x;
    int bc, f;
    if (MODE != 2) { bc = blk / NFRAMES; f = blk - bc*NFRAMES; }
    else           { bc = blk / nfp;     f = pass + 4*(blk - bc*nfp); }

    const float2* w2c = (const float2*)window;
    const unsigned* grow = gains + (size_t)(bc*NFR2 + f) * RSTR;
    uint2* spx = spec + (size_t)(bc*NFRAMES + f) * SPSTR;

    if (MODE != 2) {
        // scale + repack directly from fp16 spec pairs (no FFT, no unpack)
#pragma unroll
        for (int j = 0; j < 4; ++j) {
            int m = tid + NT*j;
            uint2 v = spx[m];
            float4 wpv = wp[m];
            cplx gg = unpackh2(grow[m]);
            cplx XSk  = scale_bin(unpackh2(v.x), gg.x);
            cplx XSk2 = scale_bin(unpackh2(v.y), gg.y);
            repack_pair(s, XSk, XSk2, C2(wpv.x, wpv.y),
                        __float_as_int(wpv.z), __float_as_int(wpv.w));
        }
        if (tid == 0) {
            uint2 v = spx[1024];
            cplx gg = unpackh2(grow[1024]);
            cplx XS = scale_bin(unpackh2(v.x), gg.x);
            s[SW(2)] = C2(XS.x, -XS.y);     // Z' = conj(XS)
        }
        __syncthreads();
    } else {
        {   // fused load + forward round A
            const float2* a2c = (const float2*)(audio + (size_t)bc*NSAMP + (size_t)f*NHOP);
            cplx d[8];
#pragma unroll
            for (int q = 0; q < 8; ++q) {
                int n = tid + 256*q;
                float2 u = a2c[n], w = w2c[n];
                d[q] = C2(u.x*w.x, u.y*w.y);
            }
            r8f(d, tw12, tw3t, tid, 0);
#pragma unroll
            for (int q = 0; q < 8; ++q) s[SW(tid + 256*q)] = d[q];
        }
        fft_fwd_rest(s, tw12, tw3t, tid);
        // unpack + scale + repack in place
#pragma unroll
        for (int j = 0; j < 4; ++j) {
            int m = tid + NT*j;
            float4 wpv = wp[m];
            int p  = __float_as_int(wpv.z);
            int p2 = __float_as_int(wpv.w);
            cplx Zk  = s[SW(p)];
            cplx Zk2 = s[SW(p2)];
            cplx Ze = C2(0.5f*(Zk.x + Zk2.x), 0.5f*(Zk.y - Zk2.y));
            cplx Zo = C2(0.5f*(Zk.y + Zk2.y), -0.5f*(Zk.x - Zk2.x));
            cplx W  = C2(wpv.x, wpv.y);
            cplx V  = cmul(W, Zo);
            cplx Xk  = Ze + V;
            cplx Xk2 = C2(Ze.x - V.x, V.y - Ze.y);
            cplx gg = unpackh2(grow[m]);
            cplx XSk  = scale_bin(Xk,  gg.x);
            cplx XSk2 = scale_bin(Xk2, gg.y);
            repack_pair(s, XSk, XSk2, W, p, p2);
        }
        if (tid == 0) {
            cplx Z  = s[SW(2)];
            cplx gg = unpackh2(grow[1024]);
            cplx XS = scale_bin(C2(Z.x, -Z.y), gg.x);
            s[SW(2)] = C2(XS.x, -XS.y);
        }
        __syncthreads();
    }

    fft_inv_rest(s, tw12, tw3t, tid);

    const float invn = 1.0f/2048.0f;
    {   // round A' (stride 256) in registers -> global write
        cplx d[8];
#pragma unroll
        for (int q = 0; q < 8; ++q) d[q] = s[SW(tid + 256*q)];
        r8i(d, tw12, tw3t, tid, 0);
        if (MODE == 1) {
            unsigned* caH = (unsigned*)spx;      // overwrite spec row with fp16 ca
#pragma unroll
            for (int q = 0; q < 8; ++q) {
                int n = tid + 256*q;
                float2 w = w2c[n];
                caH[n] = packh2(d[q].x*w.x*invn, d[q].y*w.y*invn);
            }
        } else {
            float2* dst2 = (float2*)(out + (size_t)bc*NSAMP + (size_t)f*NHOP);
#pragma unroll
            for (int q = 0; q < 8; ++q) {
                int n = tid + 256*q;
                float2 w = w2c[n];
                float2 o = dst2[n];
                o.x += d[q].x * w.x * invn;
                o.y += d[q].y * w.y * invn;
                dst2[n] = o;
            }
        }
    }
}

// ---------------- kernel 4: overlap-add gather over fp16 ca rows (in spec buffer) ----------------
__global__ __launch_bounds__(NT) void k_ola(
    const uint2* __restrict__ spec, float* __restrict__ out)
{
    const int blk = blockIdx.x;
    const int bc = blk >> 9;          // 512 tiles of 1024 samples
    const int ti = blk & 511;
    const int tid = threadIdx.x;
    float4 acc = make_float4(0.f, 0.f, 0.f, 0.f);
    int flo = ti - 3; if (flo < 0) flo = 0;
    int fhi = ti; if (fhi > NFRAMES - 1) fhi = NFRAMES - 1;
    for (int f = flo; f <= fhi; ++f) {
        const uint2* row = spec + (size_t)(bc*NFRAMES + f) * SPSTR;
        uint2 v = row[(ti - f)*256 + tid];
        cplx a = unpackh2(v.x), b = unpackh2(v.y);
        acc.x += a.x; acc.y += a.y; acc.z += b.x; acc.w += b.y;
    }
    ((float4*)(out + (size_t)bc*NSAMP))[ti*256 + tid] = acc;
}

extern "C" void kernel_launch(void* const* d_in, const int* in_sizes, int n_in,
                              void* d_out, int out_size, void* d_ws, size_t ws_size,
                              hipStream_t stream)
{
    const float* audio  = (const float*)d_in[0];
    const float* window = (const float*)d_in[1];
    const float* thr    = (const float*)d_in[2];
    const float* ratio  = (const float*)d_in[3];
    const float* makeup = (const float*)d_in[4];
    const float* knee   = (const float*)d_in[5];
    float* out = (float*)d_out;

    char* base = (char*)d_ws;
    float4* tw12 = (float4*)base;
    float2* tw3t = (float2*)(base + 8192);
    float4* wp   = (float4*)(base + 16384);
    float4* pa   = (float4*)(base + 32768);
    float4* pb   = (float4*)(base + 49152);
    float2* mkq2 = (float2*)(base + 65536);
    unsigned* gr = (unsigned*)(base + WSHDR);
    const size_t grB = (size_t)NBC*NFR2*RSTR*sizeof(unsigned);           // 34.1 MB
    const size_t spB = (size_t)NBC*NFRAMES*SPSTR*sizeof(uint2);          // 66.8 MB
    const size_t needB = WSHDR + grB + spB;          // fp16 ca reuses spec buffer

    dim3 blkd(NT);
    k_init<<<dim3((TWN + 1025 + NT - 1)/NT), blkd, 0, stream>>>(
        thr, ratio, knee, makeup, tw12, tw3t, wp, pa, pb, mkq2);

    int sblocks = (NBC*RSTR + STH - 1)/STH;
    if (ws_size >= needB) {
        uint2* spec = (uint2*)(base + WSHDR + grB);
        k_fwd<1><<<dim3(NBC*NFRAMES), blkd, 0, stream>>>(
            audio, window, thr, ratio, knee, tw12, tw3t, wp, pa, pb, gr, spec);
        k_smooth<<<dim3(sblocks), dim3(STH), 0, stream>>>(gr, mkq2);
        k_inv<1><<<dim3(NBC*NFRAMES), blkd, 0, stream>>>(
            audio, window, gr, tw12, tw3t, wp, spec, out, 0, 0);
        k_ola<<<dim3(NBC*512), blkd, 0, stream>>>(spec, out);
    } else {
        hipMemsetAsync(d_out, 0, (size_t)out_size*sizeof(float), stream);
        uint2* spec = (uint2*)(base + WSHDR + grB);   // unused in MODE 2
        k_fwd<0><<<dim3(NBC*NFRAMES), blkd, 0, stream>>>(
            audio, window, thr, ratio, knee, tw12, tw3t, wp, pa, pb, gr, spec);
        k_smooth<<<dim3(sblocks), dim3(STH), 0, stream>>>(gr, mkq2);
        for (int pass = 0; pass < 4; ++pass) {
            int nfp = (NFRAMES - pass + 3) / 4;
            k_inv<2><<<dim3(NBC*nfp), blkd, 0, stream>>>(
                audio, window, gr, tw12, tw3t, wp, spec, out, pass, nfp);
        }
    }
}

// Round 13
// 167.962 us; speedup vs baseline: 1.9060x; 1.0039x over previous
//
#include <hip/hip_runtime.h>
#include <hip/hip_fp16.h>

#define NFFT     4096
#define NC       2048      // complex FFT length (real-packed)
#define NHOP     1024
#define NK       2049
#define NBC      16
#define NSAMP    524288
#define NFRAMES  509
#define NFR2     520       // padded frame rows for branch-free smooth prefetch
#define NT       256
#define STH      64        // k_smooth block size
#define SPSTR    1025      // spec row stride in uint2 (1024 pairs + bin1024)
#define RSTR     1025      // gr row stride in uint (1024 pairs + bin1024)

#define A_COEFF 0.0022650046943f     // 1 - exp(-1/441)
#define R_COEFF 0.00022673165872f    // 1 - exp(-1/4410)
#define DB2LIN_LOG2 0.16609640474436812f  // log2(10)/20
#define DB_LOG2     6.02059991327962390f  // 20*log10(2)
#define PI_D 3.14159265358979323846264338327950288

// LDS swizzle: ~2-way max at every FFT stage
#define SW(e) ((e) + 7*((e)>>5))
#define SWSZ 2489      // SW(2047)+1  -> 19912 B LDS = 8 blocks/CU
#define TWN  292       // radix-8 stage tables: 256(A) + 32(B) + 4(C)
// ws header (bytes): tw12@0, tw3t@8192, wp@16384, pa@32768, pb@49152, mkq2@65536
#define WSHDR 131072

// XCD-aware block swizzle (8 XCDs, grid divisible by 8 -> bijective):
// dispatcher sends consecutive blockIdx round-robin to XCDs; remap so each
// XCD works a CONTIGUOUS frame range -> sliding audio/ca window stays in its L2.
__device__ __forceinline__ int xswz(int b, int cpx){ return (b & 7)*cpx + (b >> 3); }

// packed-f32 complex: lane0=re, lane1=im -> v_pk_* dual-issue on gfx950
typedef float cplx __attribute__((ext_vector_type(2)));
#define C2(a,b) ((cplx){(float)(a), (float)(b)})

__device__ __forceinline__ cplx cmul(cplx a, cplx b){
    cplx p = C2(a.x, a.x) * b;                 // (ax*br, ax*bi)
    cplx q = C2(a.y, a.y) * C2(b.y, b.x);      // (ay*bi, ay*br)
    return C2(p.x - q.x, p.y + q.y);           // pk_add with neg_lo
}
__device__ __forceinline__ cplx cmulc(cplx a, cplx b){   // a * conj(b)
    cplx p = C2(a.x, a.x) * b;
    cplx q = C2(a.y, a.y) * C2(b.y, b.x);
    return C2(p.x + q.x, q.y - p.y);
}

union HU { unsigned u; __half2 h; };
__device__ __forceinline__ unsigned packh2(float a, float b){
    HU x; x.h = __floats2half2_rn(a, b); return x.u;
}
__device__ __forceinline__ cplx unpackh2(unsigned v){
    HU x; x.u = v; float2 r = __half22float2(x.h); return C2(r.x, r.y);
}

#define RSQRT2 0.70710678118654752f

// mixed-radix (8,8,8,4) digit scramble (host-side tables only)
__device__ __forceinline__ int revm(int p){
    return (p>>8) + 8*((p>>5)&7) + 64*((p>>2)&7) + 512*(p&3);
}
__device__ __forceinline__ int pmap(int k){
    return ((k&7)<<8) | (((k>>3)&7)<<5) | (((k>>6)&7)<<2) | ((k>>9)&3);
}
__device__ __forceinline__ int p_of_m(int m){ return ((m>>1)<<2) | (m&1); }

// ---------------- radix-8 forward core: butterfly then twiddle, in place ----------------
__device__ __forceinline__ void r8f(cplx* d, const float4* __restrict__ tw12,
                                    const float2* __restrict__ tw3t, int n, int toff){
    cplx EA0=d[0]+d[4], EA1=d[0]-d[4];
    cplx EB0=d[2]+d[6], EB1=d[2]-d[6];
    cplx OA0=d[1]+d[5], OA1=d[1]-d[5];
    cplx OB0=d[3]+d[7], OB1=d[3]-d[7];
    cplx E0=EA0+EB0, E2=EA0-EB0;
    cplx E1=C2(EA1.x+EB1.y, EA1.y-EB1.x);   // EA1 - i*EB1
    cplx E3=C2(EA1.x-EB1.y, EA1.y+EB1.x);   // EA1 + i*EB1
    cplx O0=OA0+OB0, O2=OA0-OB0;
    cplx O1=C2(OA1.x+OB1.y, OA1.y-OB1.x);
    cplx O3=C2(OA1.x-OB1.y, OA1.y+OB1.x);
    const float c = RSQRT2;
    cplx t1=C2(c*(O1.x+O1.y), c*(O1.y-O1.x));   // w8^1 * O1
    cplx u2=C2(O2.y, -O2.x);                    // -i * O2
    cplx v3=C2(c*(O3.y-O3.x), -c*(O3.x+O3.y));  // w8^3 * O3
    float4 w12 = tw12[toff + n];
    cplx w1 = C2(w12.x, w12.y), w2 = C2(w12.z, w12.w);
    float2 w3l = tw3t[toff + n];
    cplx w3 = C2(w3l.x, w3l.y);
    cplx w4 = cmul(w2,w2), w5 = cmul(w2,w3), w6 = cmul(w3,w3), w7 = cmul(w3,w4);
    d[0] = E0+O0;
    d[1] = cmul(E1+t1, w1);
    d[2] = cmul(E2+u2, w2);
    d[3] = cmul(E3+v3, w3);
    d[4] = cmul(E0-O0, w4);
    d[5] = cmul(E1-t1, w5);
    d[6] = cmul(E2-u2, w6);
    d[7] = cmul(E3-v3, w7);
}

// ---------------- radix-8 inverse core: conj-twiddle then inverse butterfly ----------------
__device__ __forceinline__ void r8i(cplx* d, const float4* __restrict__ tw12,
                                    const float2* __restrict__ tw3t, int n, int toff){
    float4 w12 = tw12[toff + n];
    cplx w1 = C2(w12.x, w12.y), w2 = C2(w12.z, w12.w);
    float2 w3l = tw3t[toff + n];
    cplx w3 = C2(w3l.x, w3l.y);
    cplx w4 = cmul(w2,w2), w5 = cmul(w2,w3), w6 = cmul(w3,w3), w7 = cmul(w3,w4);
    d[1]=cmulc(d[1],w1); d[2]=cmulc(d[2],w2); d[3]=cmulc(d[3],w3); d[4]=cmulc(d[4],w4);
    d[5]=cmulc(d[5],w5); d[6]=cmulc(d[6],w6); d[7]=cmulc(d[7],w7);
    cplx EA0=d[0]+d[4], EA1=d[0]-d[4];
    cplx EB0=d[2]+d[6], EB1=d[2]-d[6];
    cplx OA0=d[1]+d[5], OA1=d[1]-d[5];
    cplx OB0=d[3]+d[7], OB1=d[3]-d[7];
    cplx E0=EA0+EB0, E2=EA0-EB0;
    cplx E1=C2(EA1.x-EB1.y, EA1.y+EB1.x);   // EA1 + i*EB1
    cplx E3=C2(EA1.x+EB1.y, EA1.y-EB1.x);
    cplx O0=OA0+OB0, O2=OA0-OB0;
    cplx O1=C2(OA1.x-OB1.y, OA1.y+OB1.x);
    cplx O3=C2(OA1.x+OB1.y, OA1.y-OB1.x);
    const float c = RSQRT2;
    cplx t1=C2(c*(O1.x-O1.y), c*(O1.y+O1.x));    // conj(w8)*O1
    cplx u2=C2(-O2.y, O2.x);                     // +i*O2
    cplx v3=C2(-c*(O3.x+O3.y), c*(O3.x-O3.y));   // conj(w8^3)*O3
    d[0] = E0+O0;
    d[1] = E1+t1;
    d[2] = E2+u2;
    d[3] = E3+v3;
    d[4] = E0-O0;
    d[5] = E1-t1;
    d[6] = E2-u2;
    d[7] = E3-v3;
}

// rounds B, C, D of forward FFT (round A done by caller in registers)
__device__ __forceinline__ void fft_fwd_rest(cplx* s, const float4* __restrict__ tw12,
                                             const float2* __restrict__ tw3t, int tid){
    __syncthreads();
    {   // round B, stride 32
        int base = (tid>>5)*256 + (tid&31);
        cplx d[8];
#pragma unroll
        for (int q = 0; q < 8; ++q) d[q] = s[SW(base + 32*q)];
        r8f(d, tw12, tw3t, tid&31, 256);
#pragma unroll
        for (int q = 0; q < 8; ++q) s[SW(base + 32*q)] = d[q];
    }
    __syncthreads();
    {   // round C, stride 4
        int base = (tid>>2)*32 + (tid&3);
        cplx d[8];
#pragma unroll
        for (int q = 0; q < 8; ++q) d[q] = s[SW(base + 4*q)];
        r8f(d, tw12, tw3t, tid&3, 288);
#pragma unroll
        for (int q = 0; q < 8; ++q) s[SW(base + 4*q)] = d[q];
    }
    __syncthreads();
    {   // round D: radix-4 span-1, trivial twiddle, contiguous 8/thread
        int g8 = 8*tid;
#pragma unroll
        for (int h = 0; h < 2; ++h) {
            int b4 = g8 + 4*h;
            cplx x0=s[SW(b4)], x1=s[SW(b4+1)], x2=s[SW(b4+2)], x3=s[SW(b4+3)];
            cplx A0=x0+x2, A1=x0-x2;
            cplx B0=x1+x3, B1=x1-x3;
            s[SW(b4)]   = A0+B0;
            s[SW(b4+1)] = C2(A1.x + B1.y, A1.y - B1.x);  // A1 - i*B1
            s[SW(b4+2)] = A0-B0;
            s[SW(b4+3)] = C2(A1.x - B1.y, A1.y + B1.x);  // A1 + i*B1
        }
    }
    __syncthreads();
}

// rounds D', C', B' of inverse FFT; caller does round A' in registers afterwards
__device__ __forceinline__ void fft_inv_rest(cplx* s, const float4* __restrict__ tw12,
                                             const float2* __restrict__ tw3t, int tid){
    {   // radix-4 span-1 inverse
        int g8 = 8*tid;
#pragma unroll
        for (int h = 0; h < 2; ++h) {
            int b4 = g8 + 4*h;
            cplx z0=s[SW(b4)], z1=s[SW(b4+1)], z2=s[SW(b4+2)], z3=s[SW(b4+3)];
            cplx A0=z0+z2, A1=z0-z2;
            cplx B0=z1+z3, B1=z1-z3;
            s[SW(b4)]   = A0+B0;
            s[SW(b4+1)] = C2(A1.x - B1.y, A1.y + B1.x);  // A1 + i*B1
            s[SW(b4+2)] = A0-B0;
            s[SW(b4+3)] = C2(A1.x + B1.y, A1.y - B1.x);  // A1 - i*B1
        }
    }
    __syncthreads();
    {   // C' stride 4
        int base = (tid>>2)*32 + (tid&3);
        cplx d[8];
#pragma unroll
        for (int q = 0; q < 8; ++q) d[q] = s[SW(base + 4*q)];
        r8i(d, tw12, tw3t, tid&3, 288);
#pragma unroll
        for (int q = 0; q < 8; ++q) s[SW(base + 4*q)] = d[q];
    }
    __syncthreads();
    {   // B' stride 32
        int base = (tid>>5)*256 + (tid&31);
        cplx d[8];
#pragma unroll
        for (int q = 0; q < 8; ++q) d[q] = s[SW(base + 32*q)];
        r8i(d, tw12, tw3t, tid&31, 256);
#pragma unroll
        for (int q = 0; q < 8; ++q) s[SW(base + 32*q)] = d[q];
    }
    __syncthreads();
}

// q = {th, ks, 1/kw, slope}; input is |X|^2
__device__ __forceinline__ float gr_of2(float a2, float4 q){
    float mag_db = 0.5f * DB_LOG2 * log2f(fmaxf(a2, 1e-16f));
    float over = mag_db - q.x;
    float hard = (mag_db < q.x) ? 0.0f : over*q.w;
    float kf = fminf(fmaxf((mag_db - q.y)*q.z, 0.0f), 1.0f);
    float kneeg = kf*kf*over*q.w;
    float ke = 2.0f*q.x - q.y;
    return (mag_db >= q.y && mag_db <= ke) ? kneeg : hard;
}

__device__ __forceinline__ cplx scale_bin(cplx X, float g){
    float a2 = X.x*X.x + X.y*X.y;
    if (a2 >= 1e-16f) return C2(g,g)*X;
    if (a2 > 0.f)  { float sc = g*1e-8f*rsqrtf(a2); return C2(sc,sc)*X; }
    return C2(g*1e-8f, 0.f);
}

// ---------------- init: twiddles + pair table {W, p, p2} + params + makeup pairs ----------------
__global__ __launch_bounds__(NT) void k_init(
    const float* __restrict__ thr, const float* __restrict__ ratio,
    const float* __restrict__ knee, const float* __restrict__ makeup,
    float4* __restrict__ tw12, float2* __restrict__ tw3t,
    float4* __restrict__ wp, float4* __restrict__ pa, float4* __restrict__ pb,
    float2* __restrict__ mkq2)
{
    int i = blockIdx.x*NT + threadIdx.x;
    if (i < TWN) {
        int n, len;
        if (i < 256)      { n = i;       len = 2048; }
        else if (i < 288) { n = i - 256; len = 256;  }
        else              { n = i - 288; len = 32;   }
        double ang = -2.0*PI_D*(double)n/(double)len;
        tw12[i] = make_float4((float)cos(ang), (float)sin(ang),
                              (float)cos(2.0*ang), (float)sin(2.0*ang));
        tw3t[i] = make_float2((float)cos(3.0*ang), (float)sin(3.0*ang));
    } else if (i < TWN + 1024) {
        int m = i - TWN;
        int p  = p_of_m(m);
        int k  = revm(p);
        int k2 = (k == 0) ? 2048 : 2048 - k;
        int p2 = pmap((2048 - k) & 2047);
        double ang = -PI_D*(double)k/2048.0;   // E(k/4096)
        wp[m] = make_float4((float)cos(ang), (float)sin(ang),
                            __int_as_float(p), __int_as_float(p2));
        float th = thr[k], ra = ratio[k], kw = knee[k];
        pa[m] = make_float4(th, th - 0.5f*kw, 1.0f/kw, 1.0f - 1.0f/ra);
        th = thr[k2]; ra = ratio[k2]; kw = knee[k2];
        pb[m] = make_float4(th, th - 0.5f*kw, 1.0f/kw, 1.0f - 1.0f/ra);
        mkq2[m] = make_float2(exp2f(makeup[k]  * DB2LIN_LOG2),
                              exp2f(makeup[k2] * DB2LIN_LOG2));
    } else if (i == TWN + 1024) {
        mkq2[1024] = make_float2(exp2f(makeup[1024] * DB2LIN_LOG2), 1.0f);
    }
}

// ---------------- kernel 1: STFT (round A fused with load); fp16 spec pairs + packed gr ----------------
template<int STORESPEC>
__global__ __launch_bounds__(NT, 8) void k_fwd(
    const float* __restrict__ audio, const float* __restrict__ window,
    const float* __restrict__ thr, const float* __restrict__ ratio,
    const float* __restrict__ knee,
    const float4* __restrict__ tw12, const float2* __restrict__ tw3t,
    const float4* __restrict__ wp, const float4* __restrict__ pa,
    const float4* __restrict__ pb,
    unsigned* __restrict__ gr, uint2* __restrict__ spec)
{
    __shared__ cplx s[SWSZ];
    const int tid = threadIdx.x;
    const int blk = xswz(blockIdx.x, (NBC*NFRAMES)/8);   // XCD-contiguous frames
    const int bc  = blk / NFRAMES;
    const int f   = blk - bc*NFRAMES;

    const float2* a2c = (const float2*)(audio + (size_t)bc*NSAMP + (size_t)f*NHOP);
    const float2* w2c = (const float2*)window;
    {   // fused load + round A (stride 256), registers only
        cplx d[8];
#pragma unroll
        for (int q = 0; q < 8; ++q) {
            int n = tid + 256*q;
            float2 u = a2c[n], w = w2c[n];
            d[q] = C2(u.x*w.x, u.y*w.y);     // z[n] = x[2n]w + i x[2n+1]w
        }
        r8f(d, tw12, tw3t, tid, 0);
#pragma unroll
        for (int q = 0; q < 8; ++q) s[SW(tid + 256*q)] = d[q];
    }
    fft_fwd_rest(s, tw12, tw3t, tid);

    unsigned* grow = gr + (size_t)(bc*NFR2 + f) * RSTR;
    uint2* spx = spec + (size_t)(bc*NFRAMES + f) * SPSTR;
#pragma unroll
    for (int j = 0; j < 4; ++j) {
        int m  = tid + NT*j;
        float4 wpv = wp[m];
        int p  = __float_as_int(wpv.z);
        int p2 = __float_as_int(wpv.w);
        cplx Zk  = s[SW(p)];
        cplx Zk2 = s[SW(p2)];
        cplx Ze = C2(0.5f*(Zk.x + Zk2.x), 0.5f*(Zk.y - Zk2.y));
        cplx Zo = C2(0.5f*(Zk.y + Zk2.y), -0.5f*(Zk.x - Zk2.x));
        cplx W  = C2(wpv.x, wpv.y);
        cplx V  = cmul(W, Zo);
        cplx Xk  = Ze + V;                              // X[k]
        cplx Xk2 = C2(Ze.x - V.x, V.y - Ze.y);          // X[2048-k]
        if (STORESPEC)
            spx[m] = make_uint2(packh2(Xk.x, Xk.y), packh2(Xk2.x, Xk2.y));
        grow[m] = packh2(gr_of2(Xk.x*Xk.x + Xk.y*Xk.y,   pa[m]),
                         gr_of2(Xk2.x*Xk2.x + Xk2.y*Xk2.y, pb[m]));
    }
    if (tid == 0) {   // self-paired bin 1024 at slot pmap(1024)=2: X = conj(Z)
        cplx Z = s[SW(2)];
        if (STORESPEC) spx[1024] = make_uint2(packh2(Z.x, -Z.y), 0u);
        float th = thr[1024], ra = ratio[1024], kw = knee[1024];
        float4 q = make_float4(th, th - 0.5f*kw, 1.0f/kw, 1.0f - 1.0f/ra);
        grow[1024] = packh2(gr_of2(Z.x*Z.x + Z.y*Z.y, q), 0.f);
    }
}

// ---------------- kernel 2: attack/release scan; 32-frame SW pipeline, 32-frame prefetch ----------------
__device__ __forceinline__ void sm_batch8(unsigned* v, float& env1, float& env2,
                                          float2 mk, unsigned* p, int c){
    float t1[8], t2[8];
#pragma unroll
    for (int d = 0; d < 8; ++d) {
        cplx gdb = unpackh2(v[d]);
        t1[d] = exp2f(gdb.x * -DB2LIN_LOG2);     // tgt, indep of env
        t2[d] = exp2f(gdb.y * -DB2LIN_LOG2);
    }
#pragma unroll
    for (int d = 0; d < 8; ++d) {
        float c1 = (t1[d] < env1) ? A_COEFF : R_COEFF;
        env1 = fmaf(c1, t1[d] - env1, env1);
        float c2 = (t2[d] < env2) ? A_COEFF : R_COEFF;
        env2 = fmaf(c2, t2[d] - env2, env2);
        v[d] = packh2(fmaxf(env1, 1e-8f) * mk.x,
                      fmaxf(env2, 1e-8f) * mk.y);    // linear gain (log/exp cancels)
    }
#pragma unroll
    for (int d = 0; d < 8; ++d) p[(size_t)(c+d)*RSTR] = v[d];
}

__global__ __launch_bounds__(STH) void k_smooth(
    unsigned* __restrict__ gr, const float2* __restrict__ mkq2)
{
    int gid = blockIdx.x*STH + threadIdx.x;
    if (gid >= NBC*RSTR) return;
    int bc = gid / RSTR;
    int m  = gid - bc*RSTR;
    float2 mk = mkq2[m];
    unsigned* p = gr + (size_t)bc*NFR2*RSTR + m;

    float env1 = 0.f, env2 = 0.f;
    unsigned b[4][8], n[4][8];
#pragma unroll
    for (int g = 0; g < 4; ++g)
#pragma unroll
        for (int d = 0; d < 8; ++d) b[g][d] = p[(size_t)(8*g + d)*RSTR];

    for (int c = 0; c < 512; c += 32) {
        if (c < 480) {   // prefetch next 32 frames (reads <= frame 511 < NFR2)
#pragma unroll
            for (int g = 0; g < 4; ++g)
#pragma unroll
                for (int d = 0; d < 8; ++d)
                    n[g][d] = p[(size_t)(c + 32 + 8*g + d)*RSTR];
        }
#pragma unroll
        for (int g = 0; g < 4; ++g)
            sm_batch8(b[g], env1, env2, mk, p, c + 8*g);
#pragma unroll
        for (int g = 0; g < 4; ++g)
#pragma unroll
            for (int d = 0; d < 8; ++d) b[g][d] = n[g][d];
    }
}

// repack scaled pair (XSk, XSk2) of bin k into packed-spectrum LDS slots (p, p2)
__device__ __forceinline__ void repack_pair(cplx* s, cplx XSk, cplx XSk2,
                                            cplx W, int p, int p2){
    // Z'[k] = E + i*conj(W)*P ; Z'[k2] = conj(E) + i*W*conj(P)
    cplx E = C2(0.5f*(XSk.x + XSk2.x), 0.5f*(XSk.y - XSk2.y));
    cplx P = C2(0.5f*(XSk.x - XSk2.x), 0.5f*(XSk.y + XSk2.y));
    cplx Wc = C2(W.x, -W.y);
    cplx Q  = cmul(Wc, P);
    cplx Pc = C2(P.x, -P.y);
    cplx R  = cmul(W, Pc);
    s[SW(p)]  = C2(E.x - Q.y, E.y + Q.x);
    s[SW(p2)] = C2(E.x - R.y, R.x - E.y);
}

// MODE 1: spec -> scale -> ifft -> ca fp16 (in place over spec row)
// MODE 2: fallback — recompute fwd FFT from audio, scale, ifft, RMW out (4 passes)
template<int MODE>
__global__ __launch_bounds__(NT, 8) void k_inv(
    const float* __restrict__ audio, const float* __restrict__ window,
    const unsigned* __restrict__ gains,
    const float4* __restrict__ tw12, const float2* __restrict__ tw3t,
    const float4* __restrict__ wp,
    uint2* __restrict__ spec, float* __restrict__ out, int pass, int nfp)
{
    __shared__ cplx s[SWSZ];
    const int tid = threadIdx.x;
    int bc, f;
    if (MODE != 2) {
        int blk = xswz(blockIdx.x, (NBC*NFRAMES)/8);
        bc = blk / NFRAMES; f = blk - bc*NFRAMES;
    } else {
        int blk = blockIdx.x;
        bc = blk / nfp;     f = pass + 4*(blk - bc*nfp);
    }

    const float2* w2c = (const float2*)window;
    const unsigned* grow = gains + (size_t)(bc*NFR2 + f) * RSTR;
    uint2* spx = spec + (size_t)(bc*NFRAMES + f) * SPSTR;

    if (MODE != 2) {
        // scale + repack directly from fp16 spec pairs (no FFT, no unpack)
#pragma unroll
        for (int j = 0; j < 4; ++j) {
            int m = tid + NT*j;
            uint2 v = spx[m];
            float4 wpv = wp[m];
            cplx gg = unpackh2(grow[m]);
            cplx XSk  = scale_bin(unpackh2(v.x), gg.x);
            cplx XSk2 = scale_bin(unpackh2(v.y), gg.y);
            repack_pair(s, XSk, XSk2, C2(wpv.x, wpv.y),
                        __float_as_int(wpv.z), __float_as_int(wpv.w));
        }
        if (tid == 0) {
            uint2 v = spx[1024];
            cplx gg = unpackh2(grow[1024]);
            cplx XS = scale_bin(unpackh2(v.x), gg.x);
            s[SW(2)] = C2(XS.x, -XS.y);     // Z' = conj(XS)
        }
        __syncthreads();
    } else {
        {   // fused load + forward round A
            const float2* a2c = (const float2*)(audio + (size_t)bc*NSAMP + (size_t)f*NHOP);
            cplx d[8];
#pragma unroll
            for (int q = 0; q < 8; ++q) {
                int n = tid + 256*q;
                float2 u = a2c[n], w = w2c[n];
                d[q] = C2(u.x*w.x, u.y*w.y);
            }
            r8f(d, tw12, tw3t, tid, 0);
#pragma unroll
            for (int q = 0; q < 8; ++q) s[SW(tid + 256*q)] = d[q];
        }
        fft_fwd_rest(s, tw12, tw3t, tid);
        // unpack + scale + repack in place
#pragma unroll
        for (int j = 0; j < 4; ++j) {
            int m = tid + NT*j;
            float4 wpv = wp[m];
            int p  = __float_as_int(wpv.z);
            int p2 = __float_as_int(wpv.w);
            cplx Zk  = s[SW(p)];
            cplx Zk2 = s[SW(p2)];
            cplx Ze = C2(0.5f*(Zk.x + Zk2.x), 0.5f*(Zk.y - Zk2.y));
            cplx Zo = C2(0.5f*(Zk.y + Zk2.y), -0.5f*(Zk.x - Zk2.x));
            cplx W  = C2(wpv.x, wpv.y);
            cplx V  = cmul(W, Zo);
            cplx Xk  = Ze + V;
            cplx Xk2 = C2(Ze.x - V.x, V.y - Ze.y);
            cplx gg = unpackh2(grow[m]);
            cplx XSk  = scale_bin(Xk,  gg.x);
            cplx XSk2 = scale_bin(Xk2, gg.y);
            repack_pair(s, XSk, XSk2, W, p, p2);
        }
        if (tid == 0) {
            cplx Z  = s[SW(2)];
            cplx gg = unpackh2(grow[1024]);
            cplx XS = scale_bin(C2(Z.x, -Z.y), gg.x);
            s[SW(2)] = C2(XS.x, -XS.y);
        }
        __syncthreads();
    }

    fft_inv_rest(s, tw12, tw3t, tid);

    const float invn = 1.0f/2048.0f;
    {   // round A' (stride 256) in registers -> global write
        cplx d[8];
#pragma unroll
        for (int q = 0; q < 8; ++q) d[q] = s[SW(tid + 256*q)];
        r8i(d, tw12, tw3t, tid, 0);
        if (MODE == 1) {
            unsigned* caH = (unsigned*)spx;      // overwrite spec row with fp16 ca
#pragma unroll
            for (int q = 0; q < 8; ++q) {
                int n = tid + 256*q;
                float2 w = w2c[n];
                caH[n] = packh2(d[q].x*w.x*invn, d[q].y*w.y*invn);
            }
        } else {
            float2* dst2 = (float2*)(out + (size_t)bc*NSAMP + (size_t)f*NHOP);
#pragma unroll
            for (int q = 0; q < 8; ++q) {
                int n = tid + 256*q;
                float2 w = w2c[n];
                float2 o = dst2[n];
                o.x += d[q].x * w.x * invn;
                o.y += d[q].y * w.y * invn;
                dst2[n] = o;
            }
        }
    }
}

// ---------------- kernel 4: overlap-add gather over fp16 ca rows (in spec buffer) ----------------
__global__ __launch_bounds__(NT) void k_ola(
    const uint2* __restrict__ spec, float* __restrict__ out)
{
    const int blk = xswz(blockIdx.x, (NBC*512)/8);   // XCD-contiguous tiles: ca rows reused in L2
    const int bc = blk >> 9;          // 512 tiles of 1024 samples
    const int ti = blk & 511;
    const int tid = threadIdx.x;
    float4 acc = make_float4(0.f, 0.f, 0.f, 0.f);
    int flo = ti - 3; if (flo < 0) flo = 0;
    int fhi = ti; if (fhi > NFRAMES - 1) fhi = NFRAMES - 1;
    for (int f = flo; f <= fhi; ++f) {
        const uint2* row = spec + (size_t)(bc*NFRAMES + f) * SPSTR;
        uint2 v = row[(ti - f)*256 + tid];
        cplx a = unpackh2(v.x), b = unpackh2(v.y);
        acc.x += a.x; acc.y += a.y; acc.z += b.x; acc.w += b.y;
    }
    ((float4*)(out + (size_t)bc*NSAMP))[ti*256 + tid] = acc;
}

extern "C" void kernel_launch(void* const* d_in, const int* in_sizes, int n_in,
                              void* d_out, int out_size, void* d_ws, size_t ws_size,
                              hipStream_t stream)
{
    const float* audio  = (const float*)d_in[0];
    const float* window = (const float*)d_in[1];
    const float* thr    = (const float*)d_in[2];
    const float* ratio  = (const float*)d_in[3];
    const float* makeup = (const float*)d_in[4];
    const float* knee   = (const float*)d_in[5];
    float* out = (float*)d_out;

    char* base = (char*)d_ws;
    float4* tw12 = (float4*)base;
    float2* tw3t = (float2*)(base + 8192);
    float4* wp   = (float4*)(base + 16384);
    float4* pa   = (float4*)(base + 32768);
    float4* pb   = (float4*)(base + 49152);
    float2* mkq2 = (float2*)(base + 65536);
    unsigned* gr = (unsigned*)(base + WSHDR);
    const size_t grB = (size_t)NBC*NFR2*RSTR*sizeof(unsigned);           // 34.1 MB
    const size_t spB = (size_t)NBC*NFRAMES*SPSTR*sizeof(uint2);          // 66.8 MB
    const size_t needB = WSHDR + grB + spB;          // fp16 ca reuses spec buffer

    dim3 blkd(NT);
    k_init<<<dim3((TWN + 1025 + NT - 1)/NT), blkd, 0, stream>>>(
        thr, ratio, knee, makeup, tw12, tw3t, wp, pa, pb, mkq2);

    int sblocks = (NBC*RSTR + STH - 1)/STH;
    if (ws_size >= needB) {
        uint2* spec = (uint2*)(base + WSHDR + grB);
        k_fwd<1><<<dim3(NBC*NFRAMES), blkd, 0, stream>>>(
            audio, window, thr, ratio, knee, tw12, tw3t, wp, pa, pb, gr, spec);
        k_smooth<<<dim3(sblocks), dim3(STH), 0, stream>>>(gr, mkq2);
        k_inv<1><<<dim3(NBC*NFRAMES), blkd, 0, stream>>>(
            audio, window, gr, tw12, tw3t, wp, spec, out, 0, 0);
        k_ola<<<dim3(NBC*512), blkd, 0, stream>>>(spec, out);
    } else {
        hipMemsetAsync(d_out, 0, (size_t)out_size*sizeof(float), stream);
        uint2* spec = (uint2*)(base + WSHDR + grB);   // unused in MODE 2
        k_fwd<0><<<dim3(NBC*NFRAMES), blkd, 0, stream>>>(
            audio, window, thr, ratio, knee, tw12, tw3t, wp, pa, pb, gr, spec);
        k_smooth<<<dim3(sblocks), dim3(STH), 0, stream>>>(gr, mkq2);
        for (int pass = 0; pass < 4; ++pass) {
            int nfp = (NFRAMES - pass + 3) / 4;
            k_inv<2><<<dim3(NBC*nfp), blkd, 0, stream>>>(
                audio, window, gr, tw12, tw3t, wp, spec, out, pass, nfp);
        }
    }
}